// Round 18
// baseline (207.030 us; speedup 1.0000x reference)
//
#include <hip/hip_runtime.h>
#include <math.h>

#define SLOPE 0.2f
#define LOG2E 1.4426950408889634f

// ---------------- block-specialized gemm ∥ histogram (one launch) --------
// Blocks [0, nbGemm): gemm z = h @ W^T. 64 nodes x 32 chans per block
// (blockIdx&1 picks channel half), 2x4 register tile, W^T in LDS [128][36]
// with XOR swizzle. NO atomics before this path's barrier.
// Blocks [nbGemm, ...): histogram, 4 edges/thread, rank = atomic return.
// No barrier in this path -> atomic latency never gates a barrier; the two
// block populations co-schedule on the CUs.
__global__ __launch_bounds__(256, 8) void gemm_hist_kernel(const float* __restrict__ h,
                                                           const float* __restrict__ W,
                                                           float* __restrict__ z,
                                                           const int* __restrict__ dst,
                                                           int* __restrict__ cnt,
                                                           int* __restrict__ rank,
                                                           int n, int ne, int nbGemm) {
    if ((int)blockIdx.x >= nbGemm) {
        // ---- histogram-only block ----
        int i = (blockIdx.x - nbGemm) * 256 + threadIdx.x;
        int base = i * 4;
        if (base + 3 < ne) {
            int4 d = *(const int4*)(dst + base);
            int4 r;
            r.x = atomicAdd(&cnt[d.x], 1);
            r.y = atomicAdd(&cnt[d.y], 1);
            r.z = atomicAdd(&cnt[d.z], 1);
            r.w = atomicAdd(&cnt[d.w], 1);
            *(int4*)(rank + base) = r;
        } else if (base < ne) {
            for (int rr = base; rr < ne; rr++) rank[rr] = atomicAdd(&cnt[dst[rr]], 1);
        }
        return;
    }

    // ---- gemm-only block ----
    __shared__ float ws[128][36];     // 18.4 KB, W^T (swizzled cols)
    int t = threadIdx.x;
    int nblk = blockIdx.x >> 1;
    int ch0  = (blockIdx.x & 1) << 5;
    const float4* __restrict__ W4 = reinterpret_cast<const float4*>(W);
#pragma unroll
    for (int j = 0; j < 4; j++) {
        int idx = t + j * 256;            // 0..1023
        int o  = idx >> 5;                // 0..31 (local channel)
        int kq = idx & 31;                // float4 col index
        float4 w = W4[(size_t)(ch0 + o) * 32 + kq];
        int k = kq << 2;
        int col = o ^ ((kq & 7) << 2);    // XOR swizzle on og bits
        ws[k + 0][col] = w.x; ws[k + 1][col] = w.y;
        ws[k + 2][col] = w.z; ws[k + 3][col] = w.w;
    }
    __syncthreads();

    int ng = t >> 3, og = t & 7;
    int n0 = nblk * 64 + ng * 2;
    if (n0 >= n) return;                  // n even: rows n0, n0+1 both valid
    const float* __restrict__ hp = h + (size_t)n0 * 128;

    float acc[2][4] = {};
#pragma unroll 4
    for (int k = 0; k < 128; k += 4) {
        int m = (k >> 2) & 7;
        int colb = (og ^ m) << 2;
        float4 hv[2], wv[4];
#pragma unroll
        for (int i = 0; i < 2; i++) hv[i] = *(const float4*)(hp + i * 128 + k);
#pragma unroll
        for (int kk = 0; kk < 4; kk++) wv[kk] = *(const float4*)&ws[k + kk][colb];
#pragma unroll
        for (int i = 0; i < 2; i++) {
            acc[i][0] += hv[i].x * wv[0].x + hv[i].y * wv[1].x + hv[i].z * wv[2].x + hv[i].w * wv[3].x;
            acc[i][1] += hv[i].x * wv[0].y + hv[i].y * wv[1].y + hv[i].z * wv[2].y + hv[i].w * wv[3].y;
            acc[i][2] += hv[i].x * wv[0].z + hv[i].y * wv[1].z + hv[i].z * wv[2].z + hv[i].w * wv[3].z;
            acc[i][3] += hv[i].x * wv[0].w + hv[i].y * wv[1].w + hv[i].z * wv[2].w + hv[i].w * wv[3].w;
        }
    }
#pragma unroll
    for (int i = 0; i < 2; i++) {
        *(float4*)&z[(size_t)(n0 + i) * 64 + ch0 + og * 4] =
            make_float4(acc[i][0], acc[i][1], acc[i][2], acc[i][3]);
    }
}

// ------------------------------------------------- scan (4096/block) -----
__global__ __launch_bounds__(256) void scan1(const int* __restrict__ cnt,
                                             int* __restrict__ starts,
                                             int* __restrict__ bsums, int n) {
    __shared__ int ls[256];
    int tbase = blockIdx.x * 4096 + threadIdx.x * 16;
    int v[16];
    int s = 0;
#pragma unroll
    for (int k = 0; k < 16; k++) {
        int idx = tbase + k;
        int c = idx < n ? cnt[idx] : 0;
        v[k] = c; s += c;
    }
    ls[threadIdx.x] = s;
    __syncthreads();
    for (int off = 1; off < 256; off <<= 1) {
        int t = threadIdx.x >= off ? ls[threadIdx.x - off] : 0;
        __syncthreads();
        ls[threadIdx.x] += t;
        __syncthreads();
    }
    int run = ls[threadIdx.x] - s;
    if (threadIdx.x == 255) bsums[blockIdx.x] = ls[255];
#pragma unroll
    for (int k = 0; k < 16; k++) {
        int idx = tbase + k;
        if (idx < n) starts[idx] = run;
        run += v[k];
    }
}

// scan3: add the cross-block prefix (each block redundantly sums <=24
// bsums -- L2-hot) and set starts[n]. Replaces the serial scan2 launch.
__global__ __launch_bounds__(256) void scan3(int* __restrict__ starts,
                                             const int* __restrict__ bsums,
                                             int n, int ne) {
    __shared__ int base_s;
    int i = blockIdx.x * 256 + threadIdx.x;
    if (threadIdx.x == 0) {
        int reg = (int)(blockIdx.x >> 4);          // 4096-region = 16 blocks
        int s = 0;
        for (int b = 0; b < reg; b++) s += bsums[b];
        base_s = s;
        if (blockIdx.x == 0) starts[n] = ne;
    }
    __syncthreads();
    if (i < n) starts[i] += base_s;
}

// --------------- scatter src into CSR (rank-based, 8 edges/thread) -------
__global__ __launch_bounds__(256) void scatter8_kernel(const int* __restrict__ src,
                                                       const int* __restrict__ dst,
                                                       const int* __restrict__ starts,
                                                       const int* __restrict__ rank,
                                                       int* __restrict__ csr_src, int ne) {
    int i = blockIdx.x * 256 + threadIdx.x;
    int base = i * 8;
    if (base + 7 < ne) {
        int4 s0 = *(const int4*)(src + base),  s1 = *(const int4*)(src + base + 4);
        int4 d0 = *(const int4*)(dst + base),  d1 = *(const int4*)(dst + base + 4);
        int4 r0 = *(const int4*)(rank + base), r1 = *(const int4*)(rank + base + 4);
        csr_src[starts[d0.x] + r0.x] = s0.x;
        csr_src[starts[d0.y] + r0.y] = s0.y;
        csr_src[starts[d0.z] + r0.z] = s0.z;
        csr_src[starts[d0.w] + r0.w] = s0.w;
        csr_src[starts[d1.x] + r1.x] = s1.x;
        csr_src[starts[d1.y] + r1.y] = s1.y;
        csr_src[starts[d1.z] + r1.z] = s1.z;
        csr_src[starts[d1.w] + r1.w] = s1.w;
    } else {
        for (int r = base; r < ne; r++)
            csr_src[starts[dst[r]] + rank[r]] = src[r];
    }
}

// ------------- fused: dot + online softmax + aggregation + elu -----------
// One wave per node. lane = (g,q): g = edge slot (0..3), q = channel quad.
// 2-deep gather pipeline; exp2-domain online softmax, wave-uniform fast path.
__global__ __launch_bounds__(256) void fused_node(const float4* __restrict__ z4,
                                                  const int* __restrict__ starts,
                                                  const int* __restrict__ csr_src,
                                                  float4* __restrict__ out4, int n) {
    int node = blockIdx.x * 4 + (threadIdx.x >> 6);
    if (node >= n) return;
    int lane = threadIdx.x & 63;
    int g = lane >> 4;
    int q = lane & 15;
    int rs = starts[node], re = starts[node + 1];
    float4 zd = z4[(size_t)node * 16 + q];

    float m2 = -1e30f, denom = 0.f;
    float4 acc = make_float4(0.f, 0.f, 0.f, 0.f);

    for (int c = rs; c < re; c += 64) {
        int j = c + lane;
        int sv = j < re ? csr_src[j] : 0;
        int cn = min(64, re - c);
        bool val0 = g < cn;
        int  s0 = __shfl(sv, val0 ? g : 0);
        float4 v0 = z4[(size_t)s0 * 16 + q];
        bool val1 = 4 + g < cn;
        int  s1 = __shfl(sv, val1 ? 4 + g : 0);
        float4 v1 = z4[(size_t)s1 * 16 + q];
        for (int k = 0; k < cn; k += 4) {
            int idx2 = k + 8 + g;
            bool val2 = idx2 < cn;
            int  s2 = __shfl(sv, val2 ? idx2 : 0);
            float4 v2 = z4[(size_t)s2 * 16 + q];
            float p = v0.x * zd.x + v0.y * zd.y + v0.z * zd.z + v0.w * zd.w;
#pragma unroll
            for (int msk = 1; msk < 16; msk <<= 1) p += __shfl_xor(p, msk);
            float e = p > 0.f ? p : SLOPE * p;
            float e2 = e * LOG2E;
            e2 = val0 ? e2 : -2e30f;
            if (__any(e2 > m2)) {                 // max grew somewhere: rescale
                float mnew = fmaxf(m2, e2);
                float sc = exp2f(m2 - mnew);      // ==0 on first edge
                float ex = exp2f(e2 - mnew);      // ==0 for invalid slots
                denom = fmaf(denom, sc, ex);
                acc.x = fmaf(acc.x, sc, ex * v0.x);
                acc.y = fmaf(acc.y, sc, ex * v0.y);
                acc.z = fmaf(acc.z, sc, ex * v0.z);
                acc.w = fmaf(acc.w, sc, ex * v0.w);
                m2 = mnew;
            } else {                              // fast path: no rescale
                float ex = exp2f(e2 - m2);
                denom += ex;
                acc.x = fmaf(ex, v0.x, acc.x);
                acc.y = fmaf(ex, v0.y, acc.y);
                acc.z = fmaf(ex, v0.z, acc.z);
                acc.w = fmaf(ex, v0.w, acc.w);
            }
            v0 = v1; val0 = val1;
            v1 = v2; val1 = val2;
        }
    }
#pragma unroll
    for (int msk = 16; msk < 64; msk <<= 1) {
        float mo  = __shfl_xor(m2, msk);
        float dno = __shfl_xor(denom, msk);
        float ax = __shfl_xor(acc.x, msk);
        float ay = __shfl_xor(acc.y, msk);
        float az = __shfl_xor(acc.z, msk);
        float aw = __shfl_xor(acc.w, msk);
        float mnew = fmaxf(m2, mo);
        float ss = exp2f(m2 - mnew), so = exp2f(mo - mnew);
        denom = fmaf(denom, ss, dno * so);
        acc.x = fmaf(acc.x, ss, ax * so);
        acc.y = fmaf(acc.y, ss, ay * so);
        acc.z = fmaf(acc.z, ss, az * so);
        acc.w = fmaf(acc.w, ss, aw * so);
        m2 = mnew;
    }
    if (lane < 16) {
        float inv = denom > 0.f ? 1.f / denom : 0.f;
        float4 r; float x;
        x = acc.x * inv; r.x = x > 0.f ? x : __expf(x) - 1.f;
        x = acc.y * inv; r.y = x > 0.f ? x : __expf(x) - 1.f;
        x = acc.z * inv; r.z = x > 0.f ? x : __expf(x) - 1.f;
        x = acc.w * inv; r.w = x > 0.f ? x : __expf(x) - 1.f;
        out4[(size_t)node * 16 + q] = r;
    }
}

// -------------------------------------------------------------- launch ----
extern "C" void kernel_launch(void* const* d_in, const int* in_sizes, int n_in,
                              void* d_out, int out_size, void* d_ws, size_t ws_size,
                              hipStream_t stream) {
    const float* h   = (const float*)d_in[0];
    const float* W   = (const float*)d_in[1];
    const int*   src = (const int*)d_in[2];
    const int*   dst = (const int*)d_in[3];
    int n  = in_sizes[0] / 128;   // 100000
    int ne = in_sizes[2];         // 1600000

    // 16B-aligned layout: z | rank | csr_src | cnt | starts | bsums
    float* z       = (float*)d_ws;                    // n*64 floats (25.6 MB)
    int*   rank    = (int*)(z + (size_t)n * 64);      // ne ints (6.4 MB)
    int*   csr_src = rank + ne;                       // ne ints (6.4 MB)
    int*   cnt     = csr_src + ne;                    // n ints
    int*   starts  = cnt + n;                         // n+1 ints
    int*   bsums   = starts + ((n + 5) & ~3);         // 32 ints

    int nbGemm = ((n + 63) / 64) * 2;                 // 3126
    int nbHist = (ne / 4 + 255) / 256;                // 1563
    int nb_scan = (n + 4095) / 4096;                  // 25

    hipMemsetAsync(cnt, 0, (size_t)n * sizeof(int), stream);
    gemm_hist_kernel<<<nbGemm + nbHist, 256, 0, stream>>>(h, W, z, dst, cnt, rank,
                                                          n, ne, nbGemm);
    scan1<<<nb_scan, 256, 0, stream>>>(cnt, starts, bsums, n);
    scan3<<<(n + 255) / 256, 256, 0, stream>>>(starts, bsums, n, ne);
    scatter8_kernel<<<(ne / 8 + 255) / 256, 256, 0, stream>>>(src, dst, starts,
                                                              rank, csr_src, ne);
    fused_node<<<(n + 3) / 4, 256, 0, stream>>>((const float4*)z, starts, csr_src,
                                                (float4*)d_out, n);
}

// Round 19
// 196.777 us; speedup vs baseline: 1.0521x; 1.0521x over previous
//
#include <hip/hip_runtime.h>
#include <math.h>

#define SLOPE 0.2f
#define LOG2E 1.4426950408889634f

// ---------- interleaved gemm ∥ XCD-private histogram (one launch) --------
// blockIdx%3==2 -> histogram block g=blockIdx/3: 4 edges/thread into
// cnt8[g&7] (XCD-private copy, lines stay in one L2 -> no ping-pong),
// rank (ushort) = atomic return. Other blocks -> gemm (gemmIdx=2g+r):
// 64 nodes x 32 chans, 2x4 tile, W^T in LDS [128][36] XOR-swizzled.
// Interleave puts hist blocks on CUs from dispatch 0 -> true overlap.
__global__ __launch_bounds__(256, 8) void gemm_hist_kernel(const float* __restrict__ h,
                                                           const float* __restrict__ W,
                                                           float* __restrict__ z,
                                                           const int* __restrict__ dst,
                                                           int* __restrict__ cnt8,
                                                           unsigned short* __restrict__ rank,
                                                           int n, int ne) {
    int g = blockIdx.x / 3;
    int r = blockIdx.x % 3;
    if (r == 2) {
        // ---- histogram block ----
        int* __restrict__ cnt = cnt8 + (size_t)(g & 7) * n;
        int i = g * 256 + threadIdx.x;
        int base = i * 4;
        if (base + 3 < ne) {
            int4 d = *(const int4*)(dst + base);
            unsigned int r0 = atomicAdd(&cnt[d.x], 1);
            unsigned int r1 = atomicAdd(&cnt[d.y], 1);
            unsigned int r2 = atomicAdd(&cnt[d.z], 1);
            unsigned int r3 = atomicAdd(&cnt[d.w], 1);
            uint2 packed;
            packed.x = (r1 << 16) | (r0 & 0xFFFF);
            packed.y = (r3 << 16) | (r2 & 0xFFFF);
            *(uint2*)(rank + base) = packed;
        } else if (base < ne) {
            for (int rr = base; rr < ne; rr++)
                rank[rr] = (unsigned short)atomicAdd(&cnt[dst[rr]], 1);
        }
        return;
    }

    // ---- gemm block ----
    __shared__ float ws[128][36];     // 18.4 KB, W^T (swizzled cols)
    int t = threadIdx.x;
    int gemmIdx = 2 * g + r;
    int nblk = gemmIdx >> 1;
    int ch0  = (gemmIdx & 1) << 5;
    const float4* __restrict__ W4 = reinterpret_cast<const float4*>(W);
#pragma unroll
    for (int j = 0; j < 4; j++) {
        int idx = t + j * 256;            // 0..1023
        int o  = idx >> 5;                // 0..31 (local channel)
        int kq = idx & 31;                // float4 col index
        float4 w = W4[(size_t)(ch0 + o) * 32 + kq];
        int k = kq << 2;
        int col = o ^ ((kq & 7) << 2);    // XOR swizzle on og bits
        ws[k + 0][col] = w.x; ws[k + 1][col] = w.y;
        ws[k + 2][col] = w.z; ws[k + 3][col] = w.w;
    }
    __syncthreads();

    int ng = t >> 3, og = t & 7;
    int n0 = nblk * 64 + ng * 2;
    if (n0 >= n) return;                  // n even: rows n0, n0+1 both valid
    const float* __restrict__ hp = h + (size_t)n0 * 128;

    float acc[2][4] = {};
#pragma unroll 4
    for (int k = 0; k < 128; k += 4) {
        int m = (k >> 2) & 7;
        int colb = (og ^ m) << 2;
        float4 hv[2], wv[4];
#pragma unroll
        for (int i = 0; i < 2; i++) hv[i] = *(const float4*)(hp + i * 128 + k);
#pragma unroll
        for (int kk = 0; kk < 4; kk++) wv[kk] = *(const float4*)&ws[k + kk][colb];
#pragma unroll
        for (int i = 0; i < 2; i++) {
            acc[i][0] += hv[i].x * wv[0].x + hv[i].y * wv[1].x + hv[i].z * wv[2].x + hv[i].w * wv[3].x;
            acc[i][1] += hv[i].x * wv[0].y + hv[i].y * wv[1].y + hv[i].z * wv[2].y + hv[i].w * wv[3].y;
            acc[i][2] += hv[i].x * wv[0].z + hv[i].y * wv[1].z + hv[i].z * wv[2].z + hv[i].w * wv[3].z;
            acc[i][3] += hv[i].x * wv[0].w + hv[i].y * wv[1].w + hv[i].z * wv[2].w + hv[i].w * wv[3].w;
        }
    }
#pragma unroll
    for (int i = 0; i < 2; i++) {
        *(float4*)&z[(size_t)(n0 + i) * 64 + ch0 + og * 4] =
            make_float4(acc[i][0], acc[i][1], acc[i][2], acc[i][3]);
    }
}

// -------------------- scan over 8-copy histogram (4096/block) ------------
__global__ __launch_bounds__(256) void scan1(const int* __restrict__ cnt8,
                                             int* __restrict__ starts,
                                             int* __restrict__ bsums, int n) {
    __shared__ int ls[256];
    int tbase = blockIdx.x * 4096 + threadIdx.x * 16;
    int tot[16];
#pragma unroll
    for (int k = 0; k < 16; k++) tot[k] = 0;
    if (tbase + 15 < n) {
#pragma unroll
        for (int c = 0; c < 8; c++) {
            const int* cp = cnt8 + (size_t)c * n + tbase;
#pragma unroll
            for (int q = 0; q < 4; q++) {
                int4 v = *(const int4*)(cp + q * 4);
                tot[q * 4 + 0] += v.x; tot[q * 4 + 1] += v.y;
                tot[q * 4 + 2] += v.z; tot[q * 4 + 3] += v.w;
            }
        }
    } else {
        for (int k = 0; k < 16; k++) {
            int idx = tbase + k;
            if (idx < n)
                for (int c = 0; c < 8; c++) tot[k] += cnt8[(size_t)c * n + idx];
        }
    }
    int s = 0;
#pragma unroll
    for (int k = 0; k < 16; k++) s += tot[k];
    ls[threadIdx.x] = s;
    __syncthreads();
    for (int off = 1; off < 256; off <<= 1) {
        int t = threadIdx.x >= off ? ls[threadIdx.x - off] : 0;
        __syncthreads();
        ls[threadIdx.x] += t;
        __syncthreads();
    }
    int run = ls[threadIdx.x] - s;
    if (threadIdx.x == 255) bsums[blockIdx.x] = ls[255];
#pragma unroll
    for (int k = 0; k < 16; k++) {
        int idx = tbase + k;
        if (idx < n) starts[idx] = run;
        run += tot[k];
    }
}

// scan3: add cross-block prefix (redundant <=24-sum per block, L2-hot),
// set starts[n], and convert cnt8 in place to per-copy scatter bases.
__global__ __launch_bounds__(256) void scan3(int* __restrict__ starts,
                                             const int* __restrict__ bsums,
                                             int* __restrict__ cnt8,
                                             int n, int ne) {
    __shared__ int base_s;
    int i = blockIdx.x * 256 + threadIdx.x;
    if (threadIdx.x == 0) {
        int reg = (int)(blockIdx.x >> 4);          // 4096-region = 16 blocks
        int s = 0;
        for (int b = 0; b < reg; b++) s += bsums[b];
        base_s = s;
        if (blockIdx.x == 0) starts[n] = ne;
    }
    __syncthreads();
    if (i >= n) return;
    int b = starts[i] + base_s;
    starts[i] = b;
#pragma unroll
    for (int c = 0; c < 8; c++) {
        size_t off = (size_t)c * n + i;
        int t = cnt8[off];
        cnt8[off] = b;
        b += t;
    }
}

// ------- scatter src into CSR (rank + per-copy base, 8 edges/thread) -----
// copy of edge e = (e>>10)&7 (hist blocks own 1024-edge chunks). 8-aligned
// groups never straddle a chunk boundary.
__global__ __launch_bounds__(256) void scatter8_kernel(const int* __restrict__ src,
                                                       const int* __restrict__ dst,
                                                       const int* __restrict__ cnt8,
                                                       const unsigned short* __restrict__ rank,
                                                       int* __restrict__ csr_src,
                                                       int n, int ne) {
    int i = blockIdx.x * 256 + threadIdx.x;
    int base = i * 8;
    if (base + 7 < ne) {
        const int* __restrict__ cb = cnt8 + (size_t)((base >> 10) & 7) * n;
        int4 s0 = *(const int4*)(src + base),  s1 = *(const int4*)(src + base + 4);
        int4 d0 = *(const int4*)(dst + base),  d1 = *(const int4*)(dst + base + 4);
        uint4 rp = *(const uint4*)(rank + base);   // 8 ushorts
        csr_src[cb[d0.x] + (rp.x & 0xFFFF)] = s0.x;
        csr_src[cb[d0.y] + (rp.x >> 16)]    = s0.y;
        csr_src[cb[d0.z] + (rp.y & 0xFFFF)] = s0.z;
        csr_src[cb[d0.w] + (rp.y >> 16)]    = s0.w;
        csr_src[cb[d1.x] + (rp.z & 0xFFFF)] = s1.x;
        csr_src[cb[d1.y] + (rp.z >> 16)]    = s1.y;
        csr_src[cb[d1.z] + (rp.w & 0xFFFF)] = s1.z;
        csr_src[cb[d1.w] + (rp.w >> 16)]    = s1.w;
    } else {
        for (int e = base; e < ne; e++) {
            const int* cb = cnt8 + (size_t)((e >> 10) & 7) * n;
            csr_src[cb[dst[e]] + rank[e]] = src[e];
        }
    }
}

// ------------- fused: dot + online softmax + aggregation + elu -----------
// One wave per node. lane = (g,q): g = edge slot (0..3), q = channel quad.
// 2-deep gather pipeline; exp2-domain online softmax, wave-uniform fast path.
__global__ __launch_bounds__(256) void fused_node(const float4* __restrict__ z4,
                                                  const int* __restrict__ starts,
                                                  const int* __restrict__ csr_src,
                                                  float4* __restrict__ out4, int n) {
    int node = blockIdx.x * 4 + (threadIdx.x >> 6);
    if (node >= n) return;
    int lane = threadIdx.x & 63;
    int g = lane >> 4;
    int q = lane & 15;
    int rs = starts[node], re = starts[node + 1];
    float4 zd = z4[(size_t)node * 16 + q];

    float m2 = -1e30f, denom = 0.f;
    float4 acc = make_float4(0.f, 0.f, 0.f, 0.f);

    for (int c = rs; c < re; c += 64) {
        int j = c + lane;
        int sv = j < re ? csr_src[j] : 0;
        int cn = min(64, re - c);
        bool val0 = g < cn;
        int  s0 = __shfl(sv, val0 ? g : 0);
        float4 v0 = z4[(size_t)s0 * 16 + q];
        bool val1 = 4 + g < cn;
        int  s1 = __shfl(sv, val1 ? 4 + g : 0);
        float4 v1 = z4[(size_t)s1 * 16 + q];
        for (int k = 0; k < cn; k += 4) {
            int idx2 = k + 8 + g;
            bool val2 = idx2 < cn;
            int  s2 = __shfl(sv, val2 ? idx2 : 0);
            float4 v2 = z4[(size_t)s2 * 16 + q];
            float p = v0.x * zd.x + v0.y * zd.y + v0.z * zd.z + v0.w * zd.w;
#pragma unroll
            for (int msk = 1; msk < 16; msk <<= 1) p += __shfl_xor(p, msk);
            float e = p > 0.f ? p : SLOPE * p;
            float e2 = e * LOG2E;
            e2 = val0 ? e2 : -2e30f;
            if (__any(e2 > m2)) {                 // max grew somewhere: rescale
                float mnew = fmaxf(m2, e2);
                float sc = exp2f(m2 - mnew);      // ==0 on first edge
                float ex = exp2f(e2 - mnew);      // ==0 for invalid slots
                denom = fmaf(denom, sc, ex);
                acc.x = fmaf(acc.x, sc, ex * v0.x);
                acc.y = fmaf(acc.y, sc, ex * v0.y);
                acc.z = fmaf(acc.z, sc, ex * v0.z);
                acc.w = fmaf(acc.w, sc, ex * v0.w);
                m2 = mnew;
            } else {                              // fast path: no rescale
                float ex = exp2f(e2 - m2);
                denom += ex;
                acc.x = fmaf(ex, v0.x, acc.x);
                acc.y = fmaf(ex, v0.y, acc.y);
                acc.z = fmaf(ex, v0.z, acc.z);
                acc.w = fmaf(ex, v0.w, acc.w);
            }
            v0 = v1; val0 = val1;
            v1 = v2; val1 = val2;
        }
    }
#pragma unroll
    for (int msk = 16; msk < 64; msk <<= 1) {
        float mo  = __shfl_xor(m2, msk);
        float dno = __shfl_xor(denom, msk);
        float ax = __shfl_xor(acc.x, msk);
        float ay = __shfl_xor(acc.y, msk);
        float az = __shfl_xor(acc.z, msk);
        float aw = __shfl_xor(acc.w, msk);
        float mnew = fmaxf(m2, mo);
        float ss = exp2f(m2 - mnew), so = exp2f(mo - mnew);
        denom = fmaf(denom, ss, dno * so);
        acc.x = fmaf(acc.x, ss, ax * so);
        acc.y = fmaf(acc.y, ss, ay * so);
        acc.z = fmaf(acc.z, ss, az * so);
        acc.w = fmaf(acc.w, ss, aw * so);
        m2 = mnew;
    }
    if (lane < 16) {
        float inv = denom > 0.f ? 1.f / denom : 0.f;
        float4 r; float x;
        x = acc.x * inv; r.x = x > 0.f ? x : __expf(x) - 1.f;
        x = acc.y * inv; r.y = x > 0.f ? x : __expf(x) - 1.f;
        x = acc.z * inv; r.z = x > 0.f ? x : __expf(x) - 1.f;
        x = acc.w * inv; r.w = x > 0.f ? x : __expf(x) - 1.f;
        out4[(size_t)node * 16 + q] = r;
    }
}

// -------------------------------------------------------------- launch ----
extern "C" void kernel_launch(void* const* d_in, const int* in_sizes, int n_in,
                              void* d_out, int out_size, void* d_ws, size_t ws_size,
                              hipStream_t stream) {
    const float* h   = (const float*)d_in[0];
    const float* W   = (const float*)d_in[1];
    const int*   src = (const int*)d_in[2];
    const int*   dst = (const int*)d_in[3];
    int n  = in_sizes[0] / 128;   // 100000
    int ne = in_sizes[2];         // 1600000

    // 16B-aligned layout (38.8 MB): z | rank(u16) | cnt8 | csr_src | starts
    float*          z       = (float*)d_ws;                     // 25.6 MB
    unsigned short* rank    = (unsigned short*)(z + (size_t)n * 64); // 3.2 MB
    int*            cnt8    = (int*)(rank + ne);                // 3.2 MB
    int*            csr_src = cnt8 + (size_t)8 * n;             // 6.4 MB
    int*            starts  = csr_src + ne;                     // n+1
    int*            bsums   = starts + ((n + 5) & ~3);          // 32

    int nbHist = (ne / 4 + 255) / 256;                // 1563
    int nbTotal = nbHist * 3;                         // 4689 (gemm = 3126)
    int nb_scan = (n + 4095) / 4096;                  // 25

    hipMemsetAsync(cnt8, 0, (size_t)8 * n * sizeof(int), stream);
    gemm_hist_kernel<<<nbTotal, 256, 0, stream>>>(h, W, z, dst, cnt8, rank, n, ne);
    scan1<<<nb_scan, 256, 0, stream>>>(cnt8, starts, bsums, n);
    scan3<<<(n + 255) / 256, 256, 0, stream>>>(starts, bsums, cnt8, n, ne);
    scatter8_kernel<<<(ne / 8 + 255) / 256, 256, 0, stream>>>(src, dst, cnt8,
                                                              rank, csr_src, n, ne);
    fused_node<<<(n + 3) / 4, 256, 0, stream>>>((const float4*)z, starts, csr_src,
                                                (float4*)d_out, n);
}

// Round 21
// 192.001 us; speedup vs baseline: 1.0783x; 1.0249x over previous
//
#include <hip/hip_runtime.h>
#include <hip/hip_fp16.h>
#include <math.h>

#define SLOPE 0.2f
#define LOG2E 1.4426950408889634f

__device__ __forceinline__ unsigned short pk_f16(float x) {
    __half h = __float2half(x);
    return __half_as_ushort(h);
}
__device__ __forceinline__ float f16f(unsigned int bits_lo16) {
    return __half2float(__ushort_as_half((unsigned short)(bits_lo16 & 0xFFFFu)));
}

// ---------- interleaved gemm ∥ XCD-private histogram (one launch) --------
// blockIdx%3==2 -> histogram block g=blockIdx/3: 4 edges/thread into
// cnt8[g&7], rank (ushort) = atomic return. Other blocks -> gemm
// (gemmIdx=2g+r): 64 nodes x 32 chans, 2x4 tile, W^T in LDS XOR-swizzled.
// gemm stores z in FP16 -> halves z write + downstream gather bytes,
// 10-bit mantissa keeps dot error ~1e-2 (bf16's 8 bits failed by 5%).
__global__ __launch_bounds__(256, 8) void gemm_hist_kernel(const float* __restrict__ h,
                                                           const float* __restrict__ W,
                                                           unsigned short* __restrict__ zh,
                                                           const int* __restrict__ dst,
                                                           int* __restrict__ cnt8,
                                                           unsigned short* __restrict__ rank,
                                                           int n, int ne) {
    int g = blockIdx.x / 3;
    int r = blockIdx.x % 3;
    if (r == 2) {
        // ---- histogram block ----
        int* __restrict__ cnt = cnt8 + (size_t)(g & 7) * n;
        int i = g * 256 + threadIdx.x;
        int base = i * 4;
        if (base + 3 < ne) {
            int4 d = *(const int4*)(dst + base);
            unsigned int r0 = atomicAdd(&cnt[d.x], 1);
            unsigned int r1 = atomicAdd(&cnt[d.y], 1);
            unsigned int r2 = atomicAdd(&cnt[d.z], 1);
            unsigned int r3 = atomicAdd(&cnt[d.w], 1);
            uint2 packed;
            packed.x = (r1 << 16) | (r0 & 0xFFFF);
            packed.y = (r3 << 16) | (r2 & 0xFFFF);
            *(uint2*)(rank + base) = packed;
        } else if (base < ne) {
            for (int rr = base; rr < ne; rr++)
                rank[rr] = (unsigned short)atomicAdd(&cnt[dst[rr]], 1);
        }
        return;
    }

    // ---- gemm block ----
    __shared__ float ws[128][36];     // 18.4 KB, W^T (swizzled cols)
    int t = threadIdx.x;
    int gemmIdx = 2 * g + r;
    int nblk = gemmIdx >> 1;
    int ch0  = (gemmIdx & 1) << 5;
    const float4* __restrict__ W4 = reinterpret_cast<const float4*>(W);
#pragma unroll
    for (int j = 0; j < 4; j++) {
        int idx = t + j * 256;            // 0..1023
        int o  = idx >> 5;                // 0..31 (local channel)
        int kq = idx & 31;                // float4 col index
        float4 w = W4[(size_t)(ch0 + o) * 32 + kq];
        int k = kq << 2;
        int col = o ^ ((kq & 7) << 2);    // XOR swizzle on og bits
        ws[k + 0][col] = w.x; ws[k + 1][col] = w.y;
        ws[k + 2][col] = w.z; ws[k + 3][col] = w.w;
    }
    __syncthreads();

    int ng = t >> 3, og = t & 7;
    int n0 = nblk * 64 + ng * 2;
    if (n0 >= n) return;                  // n even: rows n0, n0+1 both valid
    const float* __restrict__ hp = h + (size_t)n0 * 128;

    float acc[2][4] = {};
#pragma unroll 4
    for (int k = 0; k < 128; k += 4) {
        int m = (k >> 2) & 7;
        int colb = (og ^ m) << 2;
        float4 hv[2], wv[4];
#pragma unroll
        for (int i = 0; i < 2; i++) hv[i] = *(const float4*)(hp + i * 128 + k);
#pragma unroll
        for (int kk = 0; kk < 4; kk++) wv[kk] = *(const float4*)&ws[k + kk][colb];
#pragma unroll
        for (int i = 0; i < 2; i++) {
            acc[i][0] += hv[i].x * wv[0].x + hv[i].y * wv[1].x + hv[i].z * wv[2].x + hv[i].w * wv[3].x;
            acc[i][1] += hv[i].x * wv[0].y + hv[i].y * wv[1].y + hv[i].z * wv[2].y + hv[i].w * wv[3].y;
            acc[i][2] += hv[i].x * wv[0].z + hv[i].y * wv[1].z + hv[i].z * wv[2].z + hv[i].w * wv[3].z;
            acc[i][3] += hv[i].x * wv[0].w + hv[i].y * wv[1].w + hv[i].z * wv[2].w + hv[i].w * wv[3].w;
        }
    }
#pragma unroll
    for (int i = 0; i < 2; i++) {
        ushort4 o4;
        o4.x = pk_f16(acc[i][0]);
        o4.y = pk_f16(acc[i][1]);
        o4.z = pk_f16(acc[i][2]);
        o4.w = pk_f16(acc[i][3]);
        *(ushort4*)&zh[(size_t)(n0 + i) * 64 + ch0 + og * 4] = o4;
    }
}

// -------------------- scan over 8-copy histogram (4096/block) ------------
__global__ __launch_bounds__(256) void scan1(const int* __restrict__ cnt8,
                                             int* __restrict__ starts,
                                             int* __restrict__ bsums, int n) {
    __shared__ int ls[256];
    int tbase = blockIdx.x * 4096 + threadIdx.x * 16;
    int tot[16];
#pragma unroll
    for (int k = 0; k < 16; k++) tot[k] = 0;
    if (tbase + 15 < n) {
#pragma unroll
        for (int c = 0; c < 8; c++) {
            const int* cp = cnt8 + (size_t)c * n + tbase;
#pragma unroll
            for (int q = 0; q < 4; q++) {
                int4 v = *(const int4*)(cp + q * 4);
                tot[q * 4 + 0] += v.x; tot[q * 4 + 1] += v.y;
                tot[q * 4 + 2] += v.z; tot[q * 4 + 3] += v.w;
            }
        }
    } else {
        for (int k = 0; k < 16; k++) {
            int idx = tbase + k;
            if (idx < n)
                for (int c = 0; c < 8; c++) tot[k] += cnt8[(size_t)c * n + idx];
        }
    }
    int s = 0;
#pragma unroll
    for (int k = 0; k < 16; k++) s += tot[k];
    ls[threadIdx.x] = s;
    __syncthreads();
    for (int off = 1; off < 256; off <<= 1) {
        int t = threadIdx.x >= off ? ls[threadIdx.x - off] : 0;
        __syncthreads();
        ls[threadIdx.x] += t;
        __syncthreads();
    }
    int run = ls[threadIdx.x] - s;
    if (threadIdx.x == 255) bsums[blockIdx.x] = ls[255];
#pragma unroll
    for (int k = 0; k < 16; k++) {
        int idx = tbase + k;
        if (idx < n) starts[idx] = run;
        run += tot[k];
    }
}

// scan3: add cross-block prefix, set starts[n], convert cnt8 in place to
// per-copy scatter bases.
__global__ __launch_bounds__(256) void scan3(int* __restrict__ starts,
                                             const int* __restrict__ bsums,
                                             int* __restrict__ cnt8,
                                             int n, int ne) {
    __shared__ int base_s;
    int i = blockIdx.x * 256 + threadIdx.x;
    if (threadIdx.x == 0) {
        int reg = (int)(blockIdx.x >> 4);          // 4096-region = 16 blocks
        int s = 0;
        for (int b = 0; b < reg; b++) s += bsums[b];
        base_s = s;
        if (blockIdx.x == 0) starts[n] = ne;
    }
    __syncthreads();
    if (i >= n) return;
    int b = starts[i] + base_s;
    starts[i] = b;
#pragma unroll
    for (int c = 0; c < 8; c++) {
        size_t off = (size_t)c * n + i;
        int t = cnt8[off];
        cnt8[off] = b;
        b += t;
    }
}

// ------- scatter src into CSR (rank + per-copy base, 8 edges/thread) -----
__global__ __launch_bounds__(256) void scatter8_kernel(const int* __restrict__ src,
                                                       const int* __restrict__ dst,
                                                       const int* __restrict__ cnt8,
                                                       const unsigned short* __restrict__ rank,
                                                       int* __restrict__ csr_src,
                                                       int n, int ne) {
    int i = blockIdx.x * 256 + threadIdx.x;
    int base = i * 8;
    if (base + 7 < ne) {
        const int* __restrict__ cb = cnt8 + (size_t)((base >> 10) & 7) * n;
        int4 s0 = *(const int4*)(src + base),  s1 = *(const int4*)(src + base + 4);
        int4 d0 = *(const int4*)(dst + base),  d1 = *(const int4*)(dst + base + 4);
        uint4 rp = *(const uint4*)(rank + base);   // 8 ushorts
        csr_src[cb[d0.x] + (rp.x & 0xFFFF)] = s0.x;
        csr_src[cb[d0.y] + (rp.x >> 16)]    = s0.y;
        csr_src[cb[d0.z] + (rp.y & 0xFFFF)] = s0.z;
        csr_src[cb[d0.w] + (rp.y >> 16)]    = s0.w;
        csr_src[cb[d1.x] + (rp.z & 0xFFFF)] = s1.x;
        csr_src[cb[d1.y] + (rp.z >> 16)]    = s1.y;
        csr_src[cb[d1.z] + (rp.w & 0xFFFF)] = s1.z;
        csr_src[cb[d1.w] + (rp.w >> 16)]    = s1.w;
    } else {
        for (int e = base; e < ne; e++) {
            const int* cb = cnt8 + (size_t)((e >> 10) & 7) * n;
            csr_src[cb[dst[e]] + rank[e]] = src[e];
        }
    }
}

// ------------- fused: dot + online softmax + aggregation + elu -----------
// One wave per node. lane = (g,q): g = edge slot (0..7), q = channel OCTET
// (0..7). z is FP16: one dwordx4 per lane = 8 channels of one edge row ->
// the wave holds 8 edges x 64 channels per gather round (2x the fp32 form,
// half the bytes). 3-step butterfly over q; exp2 online softmax; 2-deep
// pipeline; fp32 math after unpack.
__global__ __launch_bounds__(256) void fused_node(const uint4* __restrict__ zh4,
                                                  const int* __restrict__ starts,
                                                  const int* __restrict__ csr_src,
                                                  float4* __restrict__ out4, int n) {
    int node = blockIdx.x * 4 + (threadIdx.x >> 6);
    if (node >= n) return;
    int lane = threadIdx.x & 63;
    int g = lane >> 3;        // edge slot 0..7
    int q = lane & 7;         // channel octet 0..7
    int rs = starts[node], re = starts[node + 1];

    uint4 zw = zh4[(size_t)node * 8 + q];
    float zdf[8];
    zdf[0] = f16f(zw.x); zdf[1] = f16f(zw.x >> 16);
    zdf[2] = f16f(zw.y); zdf[3] = f16f(zw.y >> 16);
    zdf[4] = f16f(zw.z); zdf[5] = f16f(zw.z >> 16);
    zdf[6] = f16f(zw.w); zdf[7] = f16f(zw.w >> 16);

    float m2 = -1e30f, denom = 0.f;
    float acc[8] = {};

    for (int c = rs; c < re; c += 64) {
        int j = c + lane;
        int sv = j < re ? csr_src[j] : 0;
        int cn = min(64, re - c);
        bool val0 = g < cn;
        int  s0 = __shfl(sv, val0 ? g : 0);
        uint4 w0 = zh4[(size_t)s0 * 8 + q];
        bool val1 = 8 + g < cn;
        int  s1 = __shfl(sv, val1 ? 8 + g : 0);
        uint4 w1 = zh4[(size_t)s1 * 8 + q];
        for (int k = 0; k < cn; k += 8) {
            int idx2 = k + 16 + g;
            bool val2 = idx2 < cn;
            int  s2 = __shfl(sv, val2 ? idx2 : 0);
            uint4 w2 = zh4[(size_t)s2 * 8 + q];

            float vf[8];
            vf[0] = f16f(w0.x); vf[1] = f16f(w0.x >> 16);
            vf[2] = f16f(w0.y); vf[3] = f16f(w0.y >> 16);
            vf[4] = f16f(w0.z); vf[5] = f16f(w0.z >> 16);
            vf[6] = f16f(w0.w); vf[7] = f16f(w0.w >> 16);

            float p = vf[0] * zdf[0];
#pragma unroll
            for (int jj = 1; jj < 8; jj++) p = fmaf(vf[jj], zdf[jj], p);
#pragma unroll
            for (int msk = 1; msk < 8; msk <<= 1) p += __shfl_xor(p, msk);

            float e = p > 0.f ? p : SLOPE * p;
            float e2 = e * LOG2E;
            e2 = val0 ? e2 : -2e30f;
            if (__any(e2 > m2)) {                 // max grew somewhere: rescale
                float mnew = fmaxf(m2, e2);
                float sc = exp2f(m2 - mnew);      // ==0 on first edge
                float ex = exp2f(e2 - mnew);      // ==0 for invalid slots
                denom = fmaf(denom, sc, ex);
#pragma unroll
                for (int jj = 0; jj < 8; jj++)
                    acc[jj] = fmaf(acc[jj], sc, ex * vf[jj]);
                m2 = mnew;
            } else {                              // fast path: no rescale
                float ex = exp2f(e2 - m2);
                denom += ex;
#pragma unroll
                for (int jj = 0; jj < 8; jj++)
                    acc[jj] = fmaf(ex, vf[jj], acc[jj]);
            }
            w0 = w1; val0 = val1;
            w1 = w2; val1 = val2;
        }
    }
    // merge 8 group states (same q across g): masks 8, 16, 32
#pragma unroll
    for (int msk = 8; msk < 64; msk <<= 1) {
        float mo  = __shfl_xor(m2, msk);
        float dno = __shfl_xor(denom, msk);
        float ao[8];
#pragma unroll
        for (int jj = 0; jj < 8; jj++) ao[jj] = __shfl_xor(acc[jj], msk);
        float mnew = fmaxf(m2, mo);
        float ss = exp2f(m2 - mnew), so = exp2f(mo - mnew);
        denom = fmaf(denom, ss, dno * so);
#pragma unroll
        for (int jj = 0; jj < 8; jj++)
            acc[jj] = fmaf(acc[jj], ss, ao[jj] * so);
        m2 = mnew;
    }
    if (g == 0) {                                 // lanes 0..7: q-octet owner
        float inv = denom > 0.f ? 1.f / denom : 0.f;
        float r[8];
#pragma unroll
        for (int jj = 0; jj < 8; jj++) {
            float x = acc[jj] * inv;
            r[jj] = x > 0.f ? x : __expf(x) - 1.f;
        }
        out4[(size_t)node * 16 + q * 2 + 0] = make_float4(r[0], r[1], r[2], r[3]);
        out4[(size_t)node * 16 + q * 2 + 1] = make_float4(r[4], r[5], r[6], r[7]);
    }
}

// -------------------------------------------------------------- launch ----
extern "C" void kernel_launch(void* const* d_in, const int* in_sizes, int n_in,
                              void* d_out, int out_size, void* d_ws, size_t ws_size,
                              hipStream_t stream) {
    const float* h   = (const float*)d_in[0];
    const float* W   = (const float*)d_in[1];
    const int*   src = (const int*)d_in[2];
    const int*   dst = (const int*)d_in[3];
    int n  = in_sizes[0] / 128;   // 100000
    int ne = in_sizes[2];         // 1600000

    // 16B-aligned layout (~26 MB): zh(f16) | rank(u16) | cnt8 | csr_src | starts
    unsigned short* zh      = (unsigned short*)d_ws;             // 12.8 MB
    unsigned short* rank    = zh + (size_t)n * 64;               // 3.2 MB
    int*            cnt8    = (int*)(rank + ne);                 // 3.2 MB
    int*            csr_src = cnt8 + (size_t)8 * n;              // 6.4 MB
    int*            starts  = csr_src + ne;                      // n+1
    int*            bsums   = starts + ((n + 5) & ~3);           // 32

    int nbHist = (ne / 4 + 255) / 256;                // 1563
    int nbTotal = nbHist * 3;                         // 4689 (gemm = 3126)
    int nb_scan = (n + 4095) / 4096;                  // 25

    hipMemsetAsync(cnt8, 0, (size_t)8 * n * sizeof(int), stream);
    gemm_hist_kernel<<<nbTotal, 256, 0, stream>>>(h, W, zh, dst, cnt8, rank, n, ne);
    scan1<<<nb_scan, 256, 0, stream>>>(cnt8, starts, bsums, n);
    scan3<<<(n + 255) / 256, 256, 0, stream>>>(starts, bsums, cnt8, n, ne);
    scatter8_kernel<<<(ne / 8 + 255) / 256, 256, 0, stream>>>(src, dst, cnt8,
                                                              rank, csr_src, n, ne);
    fused_node<<<(n + 3) / 4, 256, 0, stream>>>((const uint4*)zh, starts, csr_src,
                                                (float4*)d_out, n);
}

// Round 22
// 189.026 us; speedup vs baseline: 1.0952x; 1.0157x over previous
//
#include <hip/hip_runtime.h>
#include <hip/hip_fp16.h>
#include <math.h>

#define SLOPE 0.2f
#define LOG2E 1.4426950408889634f

typedef _Float16 half8_t __attribute__((ext_vector_type(8)));
typedef float    f32x4_t __attribute__((ext_vector_type(4)));

__device__ __forceinline__ unsigned short pk_f16(float x) {
    return __half_as_ushort(__float2half(x));
}
__device__ __forceinline__ float f16f(unsigned int bits_lo16) {
    return __half2float(__ushort_as_half((unsigned short)(bits_lo16 & 0xFFFFu)));
}

// ------------------------- W -> f16 (one-time) ---------------------------
__global__ __launch_bounds__(256) void wcvt_kernel(const float* __restrict__ W,
                                                   unsigned short* __restrict__ Wh,
                                                   int total4) {
    int i = blockIdx.x * 256 + threadIdx.x;
    if (i < total4) {
        float4 w = *(const float4*)(W + (size_t)i * 4);
        ushort4 o;
        o.x = pk_f16(w.x); o.y = pk_f16(w.y);
        o.z = pk_f16(w.z); o.w = pk_f16(w.w);
        *(ushort4*)(Wh + (size_t)i * 4) = o;
    }
}

// ---------- interleaved MFMA-gemm ∥ XCD-private histogram ----------------
// blockIdx%5==4 -> histogram block g=blockIdx/5: 4 edges/thread into
// cnt8[g&7], rank(ushort)=atomic return (each hist block owns 1024
// consecutive edges -> scatter picks copy via (edge>>10)&7).
// Else gemm block gemmIdx = (blockIdx/5)*4 + blockIdx%5: 16 nodes x 64 ch.
// Wave w: 16x16 D-tile at ch0=16w via 4x mfma_f32_16x16x32_f16 (K=128).
// A=h rows (f32->f16 cvt in reg), B=Wh rows (16B load). k-mapping is the
// SAME contiguous bijection for A and B -> correctness independent of the
// HW's internal k permutation (dot is k-permutation-invariant).
// C/D: node = n0 + (lane>>4)*4 + r, ch = ch0 + (lane&15)   [m89 layout]
__global__ __launch_bounds__(256, 8) void gemm_hist_kernel(const float* __restrict__ h,
                                                           const unsigned short* __restrict__ Wh,
                                                           unsigned short* __restrict__ zh,
                                                           const int* __restrict__ dst,
                                                           int* __restrict__ cnt8,
                                                           unsigned short* __restrict__ rank,
                                                           int n, int ne, int nGemm) {
    int r5 = blockIdx.x % 5;
    int g5 = blockIdx.x / 5;
    if (r5 == 4) {
        // ---- histogram block ----
        int* __restrict__ cnt = cnt8 + (size_t)(g5 & 7) * n;
        int i = g5 * 256 + threadIdx.x;
        int base = i * 4;
        if (base + 3 < ne) {
            int4 d = *(const int4*)(dst + base);
            unsigned int r0 = atomicAdd(&cnt[d.x], 1);
            unsigned int r1 = atomicAdd(&cnt[d.y], 1);
            unsigned int r2 = atomicAdd(&cnt[d.z], 1);
            unsigned int r3 = atomicAdd(&cnt[d.w], 1);
            uint2 packed;
            packed.x = (r1 << 16) | (r0 & 0xFFFF);
            packed.y = (r3 << 16) | (r2 & 0xFFFF);
            *(uint2*)(rank + base) = packed;
        } else if (base < ne) {
            for (int rr = base; rr < ne; rr++)
                rank[rr] = (unsigned short)atomicAdd(&cnt[dst[rr]], 1);
        }
        return;
    }

    // ---- gemm block (MFMA) ----
    int gemmIdx = g5 * 4 + r5;
    int n0 = gemmIdx * 16;
    if (n0 >= n) return;
    int lane = threadIdx.x & 63;
    int wave = threadIdx.x >> 6;
    int row = lane & 15;          // A row (node) and B col (channel)
    int grp = lane >> 4;          // k-group
    int ch0 = wave * 16;

    const float* __restrict__ hp = h + (size_t)(n0 + row) * 128 + grp * 8;
    const unsigned short* __restrict__ wp = Wh + (size_t)(ch0 + row) * 128 + grp * 8;

    f32x4_t acc = {0.f, 0.f, 0.f, 0.f};
#pragma unroll
    for (int c = 0; c < 4; c++) {
        int kc = c * 32;
        float4 a0 = *(const float4*)(hp + kc);
        float4 a1 = *(const float4*)(hp + kc + 4);
        half8_t av;
        av[0] = (_Float16)a0.x; av[1] = (_Float16)a0.y;
        av[2] = (_Float16)a0.z; av[3] = (_Float16)a0.w;
        av[4] = (_Float16)a1.x; av[5] = (_Float16)a1.y;
        av[6] = (_Float16)a1.z; av[7] = (_Float16)a1.w;
        half8_t bv = *(const half8_t*)(wp + kc);
        acc = __builtin_amdgcn_mfma_f32_16x16x32_f16(av, bv, acc, 0, 0, 0);
    }
#pragma unroll
    for (int r = 0; r < 4; r++)
        zh[(size_t)(n0 + grp * 4 + r) * 64 + ch0 + row] = pk_f16(acc[r]);
}

// -------------------- scan over 8-copy histogram (4096/block) ------------
__global__ __launch_bounds__(256) void scan1(const int* __restrict__ cnt8,
                                             int* __restrict__ starts,
                                             int* __restrict__ bsums, int n) {
    __shared__ int ls[256];
    int tbase = blockIdx.x * 4096 + threadIdx.x * 16;
    int tot[16];
#pragma unroll
    for (int k = 0; k < 16; k++) tot[k] = 0;
    if (tbase + 15 < n) {
#pragma unroll
        for (int c = 0; c < 8; c++) {
            const int* cp = cnt8 + (size_t)c * n + tbase;
#pragma unroll
            for (int q = 0; q < 4; q++) {
                int4 v = *(const int4*)(cp + q * 4);
                tot[q * 4 + 0] += v.x; tot[q * 4 + 1] += v.y;
                tot[q * 4 + 2] += v.z; tot[q * 4 + 3] += v.w;
            }
        }
    } else {
        for (int k = 0; k < 16; k++) {
            int idx = tbase + k;
            if (idx < n)
                for (int c = 0; c < 8; c++) tot[k] += cnt8[(size_t)c * n + idx];
        }
    }
    int s = 0;
#pragma unroll
    for (int k = 0; k < 16; k++) s += tot[k];
    ls[threadIdx.x] = s;
    __syncthreads();
    for (int off = 1; off < 256; off <<= 1) {
        int t = threadIdx.x >= off ? ls[threadIdx.x - off] : 0;
        __syncthreads();
        ls[threadIdx.x] += t;
        __syncthreads();
    }
    int run = ls[threadIdx.x] - s;
    if (threadIdx.x == 255) bsums[blockIdx.x] = ls[255];
#pragma unroll
    for (int k = 0; k < 16; k++) {
        int idx = tbase + k;
        if (idx < n) starts[idx] = run;
        run += tot[k];
    }
}

// scan3: add cross-block prefix, set starts[n], convert cnt8 in place to
// per-copy scatter bases.
__global__ __launch_bounds__(256) void scan3(int* __restrict__ starts,
                                             const int* __restrict__ bsums,
                                             int* __restrict__ cnt8,
                                             int n, int ne) {
    __shared__ int base_s;
    int i = blockIdx.x * 256 + threadIdx.x;
    if (threadIdx.x == 0) {
        int reg = (int)(blockIdx.x >> 4);          // 4096-region = 16 blocks
        int s = 0;
        for (int b = 0; b < reg; b++) s += bsums[b];
        base_s = s;
        if (blockIdx.x == 0) starts[n] = ne;
    }
    __syncthreads();
    if (i >= n) return;
    int b = starts[i] + base_s;
    starts[i] = b;
#pragma unroll
    for (int c = 0; c < 8; c++) {
        size_t off = (size_t)c * n + i;
        int t = cnt8[off];
        cnt8[off] = b;
        b += t;
    }
}

// ------- scatter src into CSR (rank + per-copy base, 8 edges/thread) -----
__global__ __launch_bounds__(256) void scatter8_kernel(const int* __restrict__ src,
                                                       const int* __restrict__ dst,
                                                       const int* __restrict__ cnt8,
                                                       const unsigned short* __restrict__ rank,
                                                       int* __restrict__ csr_src,
                                                       int n, int ne) {
    int i = blockIdx.x * 256 + threadIdx.x;
    int base = i * 8;
    if (base + 7 < ne) {
        const int* __restrict__ cb = cnt8 + (size_t)((base >> 10) & 7) * n;
        int4 s0 = *(const int4*)(src + base),  s1 = *(const int4*)(src + base + 4);
        int4 d0 = *(const int4*)(dst + base),  d1 = *(const int4*)(dst + base + 4);
        uint4 rp = *(const uint4*)(rank + base);   // 8 ushorts
        csr_src[cb[d0.x] + (rp.x & 0xFFFF)] = s0.x;
        csr_src[cb[d0.y] + (rp.x >> 16)]    = s0.y;
        csr_src[cb[d0.z] + (rp.y & 0xFFFF)] = s0.z;
        csr_src[cb[d0.w] + (rp.y >> 16)]    = s0.w;
        csr_src[cb[d1.x] + (rp.z & 0xFFFF)] = s1.x;
        csr_src[cb[d1.y] + (rp.z >> 16)]    = s1.y;
        csr_src[cb[d1.z] + (rp.w & 0xFFFF)] = s1.z;
        csr_src[cb[d1.w] + (rp.w >> 16)]    = s1.w;
    } else {
        for (int e = base; e < ne; e++) {
            const int* cb = cnt8 + (size_t)((e >> 10) & 7) * n;
            csr_src[cb[dst[e]] + rank[e]] = src[e];
        }
    }
}

// ------------- fused: dot + online softmax + aggregation + elu -----------
// One wave per node. lane = (g,q): g = edge slot (0..7), q = channel OCTET
// (0..7). z is FP16: one dwordx4 per lane = 8 channels of one edge row ->
// 8 edges x 64 channels per gather round. 3-step butterfly; exp2 online
// softmax; 2-deep pipeline; fp32 math after unpack.
__global__ __launch_bounds__(256) void fused_node(const uint4* __restrict__ zh4,
                                                  const int* __restrict__ starts,
                                                  const int* __restrict__ csr_src,
                                                  float4* __restrict__ out4, int n) {
    int node = blockIdx.x * 4 + (threadIdx.x >> 6);
    if (node >= n) return;
    int lane = threadIdx.x & 63;
    int g = lane >> 3;        // edge slot 0..7
    int q = lane & 7;         // channel octet 0..7
    int rs = starts[node], re = starts[node + 1];

    uint4 zw = zh4[(size_t)node * 8 + q];
    float zdf[8];
    zdf[0] = f16f(zw.x); zdf[1] = f16f(zw.x >> 16);
    zdf[2] = f16f(zw.y); zdf[3] = f16f(zw.y >> 16);
    zdf[4] = f16f(zw.z); zdf[5] = f16f(zw.z >> 16);
    zdf[6] = f16f(zw.w); zdf[7] = f16f(zw.w >> 16);

    float m2 = -1e30f, denom = 0.f;
    float acc[8] = {};

    for (int c = rs; c < re; c += 64) {
        int j = c + lane;
        int sv = j < re ? csr_src[j] : 0;
        int cn = min(64, re - c);
        bool val0 = g < cn;
        int  s0 = __shfl(sv, val0 ? g : 0);
        uint4 w0 = zh4[(size_t)s0 * 8 + q];
        bool val1 = 8 + g < cn;
        int  s1 = __shfl(sv, val1 ? 8 + g : 0);
        uint4 w1 = zh4[(size_t)s1 * 8 + q];
        for (int k = 0; k < cn; k += 8) {
            int idx2 = k + 16 + g;
            bool val2 = idx2 < cn;
            int  s2 = __shfl(sv, val2 ? idx2 : 0);
            uint4 w2 = zh4[(size_t)s2 * 8 + q];

            float vf[8];
            vf[0] = f16f(w0.x); vf[1] = f16f(w0.x >> 16);
            vf[2] = f16f(w0.y); vf[3] = f16f(w0.y >> 16);
            vf[4] = f16f(w0.z); vf[5] = f16f(w0.z >> 16);
            vf[6] = f16f(w0.w); vf[7] = f16f(w0.w >> 16);

            float p = vf[0] * zdf[0];
#pragma unroll
            for (int jj = 1; jj < 8; jj++) p = fmaf(vf[jj], zdf[jj], p);
#pragma unroll
            for (int msk = 1; msk < 8; msk <<= 1) p += __shfl_xor(p, msk);

            float e = p > 0.f ? p : SLOPE * p;
            float e2 = e * LOG2E;
            e2 = val0 ? e2 : -2e30f;
            if (__any(e2 > m2)) {                 // max grew somewhere: rescale
                float mnew = fmaxf(m2, e2);
                float sc = exp2f(m2 - mnew);      // ==0 on first edge
                float ex = exp2f(e2 - mnew);      // ==0 for invalid slots
                denom = fmaf(denom, sc, ex);
#pragma unroll
                for (int jj = 0; jj < 8; jj++)
                    acc[jj] = fmaf(acc[jj], sc, ex * vf[jj]);
                m2 = mnew;
            } else {                              // fast path: no rescale
                float ex = exp2f(e2 - m2);
                denom += ex;
#pragma unroll
                for (int jj = 0; jj < 8; jj++)
                    acc[jj] = fmaf(ex, vf[jj], acc[jj]);
            }
            w0 = w1; val0 = val1;
            w1 = w2; val1 = val2;
        }
    }
    // merge 8 group states (same q across g): masks 8, 16, 32
#pragma unroll
    for (int msk = 8; msk < 64; msk <<= 1) {
        float mo  = __shfl_xor(m2, msk);
        float dno = __shfl_xor(denom, msk);
        float ao[8];
#pragma unroll
        for (int jj = 0; jj < 8; jj++) ao[jj] = __shfl_xor(acc[jj], msk);
        float mnew = fmaxf(m2, mo);
        float ss = exp2f(m2 - mnew), so = exp2f(mo - mnew);
        denom = fmaf(denom, ss, dno * so);
#pragma unroll
        for (int jj = 0; jj < 8; jj++)
            acc[jj] = fmaf(acc[jj], ss, ao[jj] * so);
        m2 = mnew;
    }
    if (g == 0) {                                 // lanes 0..7: q-octet owner
        float inv = denom > 0.f ? 1.f / denom : 0.f;
        float r[8];
#pragma unroll
        for (int jj = 0; jj < 8; jj++) {
            float x = acc[jj] * inv;
            r[jj] = x > 0.f ? x : __expf(x) - 1.f;
        }
        out4[(size_t)node * 16 + q * 2 + 0] = make_float4(r[0], r[1], r[2], r[3]);
        out4[(size_t)node * 16 + q * 2 + 1] = make_float4(r[4], r[5], r[6], r[7]);
    }
}

// -------------------------------------------------------------- launch ----
extern "C" void kernel_launch(void* const* d_in, const int* in_sizes, int n_in,
                              void* d_out, int out_size, void* d_ws, size_t ws_size,
                              hipStream_t stream) {
    const float* h   = (const float*)d_in[0];
    const float* W   = (const float*)d_in[1];
    const int*   src = (const int*)d_in[2];
    const int*   dst = (const int*)d_in[3];
    int n  = in_sizes[0] / 128;   // 100000
    int ne = in_sizes[2];         // 1600000

    // 16B-aligned layout (~26 MB): zh | rank | cnt8 | csr_src | Wh | starts
    unsigned short* zh      = (unsigned short*)d_ws;             // 12.8 MB
    unsigned short* rank    = zh + (size_t)n * 64;               // 3.2 MB
    int*            cnt8    = (int*)(rank + ne);                 // 3.2 MB
    int*            csr_src = cnt8 + (size_t)8 * n;              // 6.4 MB
    unsigned short* Wh      = (unsigned short*)(csr_src + ne);   // 16 KB
    int*            starts  = (int*)(Wh + 64 * 128);             // n+1
    int*            bsums   = starts + ((n + 5) & ~3);           // 32

    int nGemm = (n + 15) / 16;                        // 6250
    int nbHist = (ne / 4 + 255) / 256;                // 1563
    int nbTotal = nbHist * 5;                         // 7815
    int nb_scan = (n + 4095) / 4096;                  // 25

    hipMemsetAsync(cnt8, 0, (size_t)8 * n * sizeof(int), stream);
    wcvt_kernel<<<(64 * 128 / 4 + 255) / 256, 256, 0, stream>>>(W, Wh, 64 * 128 / 4);
    gemm_hist_kernel<<<nbTotal, 256, 0, stream>>>(h, Wh, zh, dst, cnt8, rank,
                                                  n, ne, nGemm);
    scan1<<<nb_scan, 256, 0, stream>>>(cnt8, starts, bsums, n);
    scan3<<<(n + 255) / 256, 256, 0, stream>>>(starts, bsums, cnt8, n, ne);
    scatter8_kernel<<<(ne / 8 + 255) / 256, 256, 0, stream>>>(src, dst, cnt8,
                                                              rank, csr_src, n, ne);
    fused_node<<<(n + 3) / 4, 256, 0, stream>>>((const uint4*)zh, starts, csr_src,
                                                (float4*)d_out, n);
}

// Round 24
// 188.558 us; speedup vs baseline: 1.0980x; 1.0025x over previous
//
#include <hip/hip_runtime.h>
#include <hip/hip_fp16.h>
#include <math.h>

#define SLOPE 0.2f
#define LOG2E 1.4426950408889634f

typedef _Float16 half8_t __attribute__((ext_vector_type(8)));
typedef _Float16 half2_t __attribute__((ext_vector_type(2)));
typedef float    f32x4_t __attribute__((ext_vector_type(4)));

__device__ __forceinline__ unsigned short pk_f16(float x) {
    return __half_as_ushort(__float2half(x));
}
__device__ __forceinline__ half2_t u2h2(unsigned int u) {
    union { unsigned int u; half2_t h; } c; c.u = u; return c.h;
}

// ------------------------- W -> f16 (one-time) ---------------------------
__global__ __launch_bounds__(256) void wcvt_kernel(const float* __restrict__ W,
                                                   unsigned short* __restrict__ Wh,
                                                   int total4) {
    int i = blockIdx.x * 256 + threadIdx.x;
    if (i < total4) {
        float4 w = *(const float4*)(W + (size_t)i * 4);
        ushort4 o;
        o.x = pk_f16(w.x); o.y = pk_f16(w.y);
        o.z = pk_f16(w.z); o.w = pk_f16(w.w);
        *(ushort4*)(Wh + (size_t)i * 4) = o;
    }
}

// ---------- interleaved MFMA-gemm ∥ XCD-private histogram ----------------
// blockIdx%5==4 -> histogram block g=blockIdx/5: 4 edges/thread into
// cnt8[g&7], rank(ushort)=atomic return. Else gemm block: 16 nodes x 64 ch,
// wave w computes a 16x16 D-tile at ch0=16w via 4x mfma_f32_16x16x32_f16.
// C/D: node = n0 + (lane>>4)*4 + r, ch = ch0 + (lane&15)   [m89 layout]
__global__ __launch_bounds__(256, 8) void gemm_hist_kernel(const float* __restrict__ h,
                                                           const unsigned short* __restrict__ Wh,
                                                           unsigned short* __restrict__ zh,
                                                           const int* __restrict__ dst,
                                                           int* __restrict__ cnt8,
                                                           unsigned short* __restrict__ rank,
                                                           int n, int ne, int nGemm) {
    int r5 = blockIdx.x % 5;
    int g5 = blockIdx.x / 5;
    if (r5 == 4) {
        // ---- histogram block ----
        int* __restrict__ cnt = cnt8 + (size_t)(g5 & 7) * n;
        int i = g5 * 256 + threadIdx.x;
        int base = i * 4;
        if (base + 3 < ne) {
            int4 d = *(const int4*)(dst + base);
            unsigned int r0 = atomicAdd(&cnt[d.x], 1);
            unsigned int r1 = atomicAdd(&cnt[d.y], 1);
            unsigned int r2 = atomicAdd(&cnt[d.z], 1);
            unsigned int r3 = atomicAdd(&cnt[d.w], 1);
            uint2 packed;
            packed.x = (r1 << 16) | (r0 & 0xFFFF);
            packed.y = (r3 << 16) | (r2 & 0xFFFF);
            *(uint2*)(rank + base) = packed;
        } else if (base < ne) {
            for (int rr = base; rr < ne; rr++)
                rank[rr] = (unsigned short)atomicAdd(&cnt[dst[rr]], 1);
        }
        return;
    }

    // ---- gemm block (MFMA) ----
    int gemmIdx = g5 * 4 + r5;
    int n0 = gemmIdx * 16;
    if (n0 >= n) return;
    int lane = threadIdx.x & 63;
    int wave = threadIdx.x >> 6;
    int row = lane & 15;          // A row (node) and B col (channel)
    int grp = lane >> 4;          // k-group
    int ch0 = wave * 16;

    const float* __restrict__ hp = h + (size_t)(n0 + row) * 128 + grp * 8;
    const unsigned short* __restrict__ wp = Wh + (size_t)(ch0 + row) * 128 + grp * 8;

    f32x4_t acc = {0.f, 0.f, 0.f, 0.f};
#pragma unroll
    for (int c = 0; c < 4; c++) {
        int kc = c * 32;
        float4 a0 = *(const float4*)(hp + kc);
        float4 a1 = *(const float4*)(hp + kc + 4);
        half8_t av;
        av[0] = (_Float16)a0.x; av[1] = (_Float16)a0.y;
        av[2] = (_Float16)a0.z; av[3] = (_Float16)a0.w;
        av[4] = (_Float16)a1.x; av[5] = (_Float16)a1.y;
        av[6] = (_Float16)a1.z; av[7] = (_Float16)a1.w;
        half8_t bv = *(const half8_t*)(wp + kc);
        acc = __builtin_amdgcn_mfma_f32_16x16x32_f16(av, bv, acc, 0, 0, 0);
    }
#pragma unroll
    for (int r = 0; r < 4; r++)
        zh[(size_t)(n0 + grp * 4 + r) * 64 + ch0 + row] = pk_f16(acc[r]);
}

// -------------------- scan over 8-copy histogram (4096/block) ------------
__global__ __launch_bounds__(256) void scan1(const int* __restrict__ cnt8,
                                             int* __restrict__ starts,
                                             int* __restrict__ bsums, int n) {
    __shared__ int ls[256];
    int tbase = blockIdx.x * 4096 + threadIdx.x * 16;
    int tot[16];
#pragma unroll
    for (int k = 0; k < 16; k++) tot[k] = 0;
    if (tbase + 15 < n) {
#pragma unroll
        for (int c = 0; c < 8; c++) {
            const int* cp = cnt8 + (size_t)c * n + tbase;
#pragma unroll
            for (int q = 0; q < 4; q++) {
                int4 v = *(const int4*)(cp + q * 4);
                tot[q * 4 + 0] += v.x; tot[q * 4 + 1] += v.y;
                tot[q * 4 + 2] += v.z; tot[q * 4 + 3] += v.w;
            }
        }
    } else {
        for (int k = 0; k < 16; k++) {
            int idx = tbase + k;
            if (idx < n)
                for (int c = 0; c < 8; c++) tot[k] += cnt8[(size_t)c * n + idx];
        }
    }
    int s = 0;
#pragma unroll
    for (int k = 0; k < 16; k++) s += tot[k];
    ls[threadIdx.x] = s;
    __syncthreads();
    for (int off = 1; off < 256; off <<= 1) {
        int t = threadIdx.x >= off ? ls[threadIdx.x - off] : 0;
        __syncthreads();
        ls[threadIdx.x] += t;
        __syncthreads();
    }
    int run = ls[threadIdx.x] - s;
    if (threadIdx.x == 255) bsums[blockIdx.x] = ls[255];
#pragma unroll
    for (int k = 0; k < 16; k++) {
        int idx = tbase + k;
        if (idx < n) starts[idx] = run;
        run += tot[k];
    }
}

// scan3: add cross-block prefix, set starts[n], convert cnt8 in place to
// per-copy scatter bases.
__global__ __launch_bounds__(256) void scan3(int* __restrict__ starts,
                                             const int* __restrict__ bsums,
                                             int* __restrict__ cnt8,
                                             int n, int ne) {
    __shared__ int base_s;
    int i = blockIdx.x * 256 + threadIdx.x;
    if (threadIdx.x == 0) {
        int reg = (int)(blockIdx.x >> 4);          // 4096-region = 16 blocks
        int s = 0;
        for (int b = 0; b < reg; b++) s += bsums[b];
        base_s = s;
        if (blockIdx.x == 0) starts[n] = ne;
    }
    __syncthreads();
    if (i >= n) return;
    int b = starts[i] + base_s;
    starts[i] = b;
#pragma unroll
    for (int c = 0; c < 8; c++) {
        size_t off = (size_t)c * n + i;
        int t = cnt8[off];
        cnt8[off] = b;
        b += t;
    }
}

// ------- scatter src into CSR (rank + per-copy base, 8 edges/thread) -----
__global__ __launch_bounds__(256) void scatter8_kernel(const int* __restrict__ src,
                                                       const int* __restrict__ dst,
                                                       const int* __restrict__ cnt8,
                                                       const unsigned short* __restrict__ rank,
                                                       int* __restrict__ csr_src,
                                                       int n, int ne) {
    int i = blockIdx.x * 256 + threadIdx.x;
    int base = i * 8;
    if (base + 7 < ne) {
        const int* __restrict__ cb = cnt8 + (size_t)((base >> 10) & 7) * n;
        int4 s0 = *(const int4*)(src + base),  s1 = *(const int4*)(src + base + 4);
        int4 d0 = *(const int4*)(dst + base),  d1 = *(const int4*)(dst + base + 4);
        uint4 rp = *(const uint4*)(rank + base);   // 8 ushorts
        csr_src[cb[d0.x] + (rp.x & 0xFFFF)] = s0.x;
        csr_src[cb[d0.y] + (rp.x >> 16)]    = s0.y;
        csr_src[cb[d0.z] + (rp.y & 0xFFFF)] = s0.z;
        csr_src[cb[d0.w] + (rp.y >> 16)]    = s0.w;
        csr_src[cb[d1.x] + (rp.z & 0xFFFF)] = s1.x;
        csr_src[cb[d1.y] + (rp.z >> 16)]    = s1.y;
        csr_src[cb[d1.z] + (rp.w & 0xFFFF)] = s1.z;
        csr_src[cb[d1.w] + (rp.w >> 16)]    = s1.w;
    } else {
        for (int e = base; e < ne; e++) {
            const int* cb = cnt8 + (size_t)((e >> 10) & 7) * n;
            csr_src[cb[dst[e]] + rank[e]] = src[e];
        }
    }
}

// ------------- fused: dot + online softmax + aggregation + elu -----------
// One wave per node. lane = (g,q): g = edge slot (0..7), q = channel OCTET
// (0..7). z is FP16, consumed PACKED: dot via 4x v_dot2_f32_f16 (no unpack),
// z_dst pre-scaled by log2e (packed mul, once) -> dot lands in exp2 domain
// (leaky-relu commutes with the positive scale). acc update uses
// fmaf(ex,(float)h,...) so the f16 extend folds into v_fma_mix_f32.
__global__ __launch_bounds__(256) void fused_node(const uint4* __restrict__ zh4,
                                                  const int* __restrict__ starts,
                                                  const int* __restrict__ csr_src,
                                                  float4* __restrict__ out4, int n) {
    int node = blockIdx.x * 4 + (threadIdx.x >> 6);
    if (node >= n) return;
    int lane = threadIdx.x & 63;
    int g = lane >> 3;        // edge slot 0..7
    int q = lane & 7;         // channel octet 0..7
    int rs = starts[node], re = starts[node + 1];

    uint4 zw = zh4[(size_t)node * 8 + q];
    const half2_t l2e = {(_Float16)LOG2E, (_Float16)LOG2E};
    half2_t zdh[4];
    zdh[0] = u2h2(zw.x) * l2e; zdh[1] = u2h2(zw.y) * l2e;
    zdh[2] = u2h2(zw.z) * l2e; zdh[3] = u2h2(zw.w) * l2e;

    float m2 = -1e30f, denom = 0.f;
    float acc[8] = {};

    for (int c = rs; c < re; c += 64) {
        int j = c + lane;
        int sv = j < re ? csr_src[j] : 0;
        int cn = min(64, re - c);
        bool val0 = g < cn;
        int  s0 = __shfl(sv, val0 ? g : 0);
        uint4 w0 = zh4[(size_t)s0 * 8 + q];
        bool val1 = 8 + g < cn;
        int  s1 = __shfl(sv, val1 ? 8 + g : 0);
        uint4 w1 = zh4[(size_t)s1 * 8 + q];
        for (int k = 0; k < cn; k += 8) {
            int idx2 = k + 16 + g;
            bool val2 = idx2 < cn;
            int  s2 = __shfl(sv, val2 ? idx2 : 0);
            uint4 w2 = zh4[(size_t)s2 * 8 + q];

            half2_t a0 = u2h2(w0.x), a1 = u2h2(w0.y);
            half2_t a2 = u2h2(w0.z), a3 = u2h2(w0.w);

            // dot in exp2 domain: 4x v_dot2_f32_f16
            float p2 = __builtin_amdgcn_fdot2(a0, zdh[0], 0.f, false);
            p2 = __builtin_amdgcn_fdot2(a1, zdh[1], p2, false);
            p2 = __builtin_amdgcn_fdot2(a2, zdh[2], p2, false);
            p2 = __builtin_amdgcn_fdot2(a3, zdh[3], p2, false);
#pragma unroll
            for (int msk = 1; msk < 8; msk <<= 1) p2 += __shfl_xor(p2, msk);

            float e2 = p2 > 0.f ? p2 : SLOPE * p2;   // leaky in log2 domain
            e2 = val0 ? e2 : -2e30f;
            if (__any(e2 > m2)) {                 // max grew somewhere: rescale
                float mnew = fmaxf(m2, e2);
                float sc = exp2f(m2 - mnew);      // ==0 on first edge
                float ex = exp2f(e2 - mnew);      // ==0 for invalid slots
                denom = fmaf(denom, sc, ex);
                acc[0] = fmaf(acc[0], sc, ex * (float)a0[0]);
                acc[1] = fmaf(acc[1], sc, ex * (float)a0[1]);
                acc[2] = fmaf(acc[2], sc, ex * (float)a1[0]);
                acc[3] = fmaf(acc[3], sc, ex * (float)a1[1]);
                acc[4] = fmaf(acc[4], sc, ex * (float)a2[0]);
                acc[5] = fmaf(acc[5], sc, ex * (float)a2[1]);
                acc[6] = fmaf(acc[6], sc, ex * (float)a3[0]);
                acc[7] = fmaf(acc[7], sc, ex * (float)a3[1]);
                m2 = mnew;
            } else {                              // fast path: v_fma_mix
                float ex = exp2f(e2 - m2);
                denom += ex;
                acc[0] = fmaf(ex, (float)a0[0], acc[0]);
                acc[1] = fmaf(ex, (float)a0[1], acc[1]);
                acc[2] = fmaf(ex, (float)a1[0], acc[2]);
                acc[3] = fmaf(ex, (float)a1[1], acc[3]);
                acc[4] = fmaf(ex, (float)a2[0], acc[4]);
                acc[5] = fmaf(ex, (float)a2[1], acc[5]);
                acc[6] = fmaf(ex, (float)a3[0], acc[6]);
                acc[7] = fmaf(ex, (float)a3[1], acc[7]);
            }
            w0 = w1; val0 = val1;
            w1 = w2; val1 = val2;
        }
    }
    // merge 8 group states (same q across g): masks 8, 16, 32
#pragma unroll
    for (int msk = 8; msk < 64; msk <<= 1) {
        float mo  = __shfl_xor(m2, msk);
        float dno = __shfl_xor(denom, msk);
        float ao[8];
#pragma unroll
        for (int jj = 0; jj < 8; jj++) ao[jj] = __shfl_xor(acc[jj], msk);
        float mnew = fmaxf(m2, mo);
        float ss = exp2f(m2 - mnew), so = exp2f(mo - mnew);
        denom = fmaf(denom, ss, dno * so);
#pragma unroll
        for (int jj = 0; jj < 8; jj++)
            acc[jj] = fmaf(acc[jj], ss, ao[jj] * so);
        m2 = mnew;
    }
    if (g == 0) {                                 // lanes 0..7: q-octet owner
        float inv = denom > 0.f ? 1.f / denom : 0.f;
        float r[8];
#pragma unroll
        for (int jj = 0; jj < 8; jj++) {
            float x = acc[jj] * inv;
            r[jj] = x > 0.f ? x : __expf(x) - 1.f;
        }
        out4[(size_t)node * 16 + q * 2 + 0] = make_float4(r[0], r[1], r[2], r[3]);
        out4[(size_t)node * 16 + q * 2 + 1] = make_float4(r[4], r[5], r[6], r[7]);
    }
}

// -------------------------------------------------------------- launch ----
extern "C" void kernel_launch(void* const* d_in, const int* in_sizes, int n_in,
                              void* d_out, int out_size, void* d_ws, size_t ws_size,
                              hipStream_t stream) {
    const float* h   = (const float*)d_in[0];
    const float* W   = (const float*)d_in[1];
    const int*   src = (const int*)d_in[2];
    const int*   dst = (const int*)d_in[3];
    int n  = in_sizes[0] / 128;   // 100000
    int ne = in_sizes[2];         // 1600000

    // 16B-aligned layout (~26 MB): zh | rank | cnt8 | csr_src | Wh | starts
    unsigned short* zh      = (unsigned short*)d_ws;             // 12.8 MB
    unsigned short* rank    = zh + (size_t)n * 64;               // 3.2 MB
    int*            cnt8    = (int*)(rank + ne);                 // 3.2 MB
    int*            csr_src = cnt8 + (size_t)8 * n;              // 6.4 MB
    unsigned short* Wh      = (unsigned short*)(csr_src + ne);   // 16 KB
    int*            starts  = (int*)(Wh + 64 * 128);             // n+1
    int*            bsums   = starts + ((n + 5) & ~3);           // 32

    int nGemm = (n + 15) / 16;                        // 6250
    int nbHist = (ne / 4 + 255) / 256;                // 1563
    int nbTotal = nbHist * 5;                         // 7815
    int nb_scan = (n + 4095) / 4096;                  // 25

    hipMemsetAsync(cnt8, 0, (size_t)8 * n * sizeof(int), stream);
    wcvt_kernel<<<(64 * 128 / 4 + 255) / 256, 256, 0, stream>>>(W, Wh, 64 * 128 / 4);
    gemm_hist_kernel<<<nbTotal, 256, 0, stream>>>(h, Wh, zh, dst, cnt8, rank,
                                                  n, ne, nGemm);
    scan1<<<nb_scan, 256, 0, stream>>>(cnt8, starts, bsums, n);
    scan3<<<(n + 255) / 256, 256, 0, stream>>>(starts, bsums, cnt8, n, ne);
    scatter8_kernel<<<(ne / 8 + 255) / 256, 256, 0, stream>>>(src, dst, cnt8,
                                                              rank, csr_src, n, ne);
    fused_node<<<(n + 3) / 4, 256, 0, stream>>>((const uint4*)zh, starts, csr_src,
                                                (float4*)d_out, n);
}

// Round 28
// 184.997 us; speedup vs baseline: 1.1191x; 1.0192x over previous
//
#include <hip/hip_runtime.h>
#include <hip/hip_fp16.h>
#include <math.h>

#define SLOPE 0.2f
#define LOG2E 1.4426950408889634f

typedef _Float16 half8_t __attribute__((ext_vector_type(8)));
typedef _Float16 half2_t __attribute__((ext_vector_type(2)));
typedef float    f32x4_t __attribute__((ext_vector_type(4)));

__device__ __forceinline__ unsigned short pk_f16(float x) {
    return __half_as_ushort(__float2half(x));
}
__device__ __forceinline__ half2_t u2h2(unsigned int u) {
    union { unsigned int u; half2_t h; } c; c.u = u; return c.h;
}

// ------------------------- W -> f16 (one-time) ---------------------------
__global__ __launch_bounds__(256) void wcvt_kernel(const float* __restrict__ W,
                                                   unsigned short* __restrict__ Wh,
                                                   int total4) {
    int i = blockIdx.x * 256 + threadIdx.x;
    if (i < total4) {
        float4 w = *(const float4*)(W + (size_t)i * 4);
        ushort4 o;
        o.x = pk_f16(w.x); o.y = pk_f16(w.y);
        o.z = pk_f16(w.z); o.w = pk_f16(w.w);
        *(ushort4*)(Wh + (size_t)i * 4) = o;
    }
}

// ---------- interleaved MFMA-gemm ∥ XCD-private histogram ----------------
// blockIdx%5==4 -> histogram block g=blockIdx/5: 4 edges/thread into
// cnt8[g&7], rank(ushort)=atomic return. Else gemm block: 16 nodes x 64 ch,
// wave w computes a 16x16 D-tile at ch0=16w via 4x mfma_f32_16x16x32_f16.
// C/D: node = n0 + (lane>>4)*4 + r, ch = ch0 + (lane&15)   [m89 layout]
__global__ __launch_bounds__(256, 8) void gemm_hist_kernel(const float* __restrict__ h,
                                                           const unsigned short* __restrict__ Wh,
                                                           unsigned short* __restrict__ zh,
                                                           const int* __restrict__ dst,
                                                           int* __restrict__ cnt8,
                                                           unsigned short* __restrict__ rank,
                                                           int n, int ne, int nGemm) {
    int r5 = blockIdx.x % 5;
    int g5 = blockIdx.x / 5;
    if (r5 == 4) {
        // ---- histogram block ----
        int* __restrict__ cnt = cnt8 + (size_t)(g5 & 7) * n;
        int i = g5 * 256 + threadIdx.x;
        int base = i * 4;
        if (base + 3 < ne) {
            int4 d = *(const int4*)(dst + base);
            unsigned int r0 = atomicAdd(&cnt[d.x], 1);
            unsigned int r1 = atomicAdd(&cnt[d.y], 1);
            unsigned int r2 = atomicAdd(&cnt[d.z], 1);
            unsigned int r3 = atomicAdd(&cnt[d.w], 1);
            uint2 packed;
            packed.x = (r1 << 16) | (r0 & 0xFFFF);
            packed.y = (r3 << 16) | (r2 & 0xFFFF);
            *(uint2*)(rank + base) = packed;
        } else if (base < ne) {
            for (int rr = base; rr < ne; rr++)
                rank[rr] = (unsigned short)atomicAdd(&cnt[dst[rr]], 1);
        }
        return;
    }

    // ---- gemm block (MFMA) ----
    int gemmIdx = g5 * 4 + r5;
    int n0 = gemmIdx * 16;
    if (n0 >= n) return;
    int lane = threadIdx.x & 63;
    int wave = threadIdx.x >> 6;
    int row = lane & 15;          // A row (node) and B col (channel)
    int grp = lane >> 4;          // k-group
    int ch0 = wave * 16;

    const float* __restrict__ hp = h + (size_t)(n0 + row) * 128 + grp * 8;
    const unsigned short* __restrict__ wp = Wh + (size_t)(ch0 + row) * 128 + grp * 8;

    f32x4_t acc = {0.f, 0.f, 0.f, 0.f};
#pragma unroll
    for (int c = 0; c < 4; c++) {
        int kc = c * 32;
        float4 a0 = *(const float4*)(hp + kc);
        float4 a1 = *(const float4*)(hp + kc + 4);
        half8_t av;
        av[0] = (_Float16)a0.x; av[1] = (_Float16)a0.y;
        av[2] = (_Float16)a0.z; av[3] = (_Float16)a0.w;
        av[4] = (_Float16)a1.x; av[5] = (_Float16)a1.y;
        av[6] = (_Float16)a1.z; av[7] = (_Float16)a1.w;
        half8_t bv = *(const half8_t*)(wp + kc);
        acc = __builtin_amdgcn_mfma_f32_16x16x32_f16(av, bv, acc, 0, 0, 0);
    }
#pragma unroll
    for (int r = 0; r < 4; r++)
        zh[(size_t)(n0 + grp * 4 + r) * 64 + ch0 + row] = pk_f16(acc[r]);
}

// -------------------- scan over 8-copy histogram (4096/block) ------------
__global__ __launch_bounds__(256) void scan1(const int* __restrict__ cnt8,
                                             int* __restrict__ starts,
                                             int* __restrict__ bsums, int n) {
    __shared__ int ls[256];
    int tbase = blockIdx.x * 4096 + threadIdx.x * 16;
    int tot[16];
#pragma unroll
    for (int k = 0; k < 16; k++) tot[k] = 0;
    if (tbase + 15 < n) {
#pragma unroll
        for (int c = 0; c < 8; c++) {
            const int* cp = cnt8 + (size_t)c * n + tbase;
#pragma unroll
            for (int q = 0; q < 4; q++) {
                int4 v = *(const int4*)(cp + q * 4);
                tot[q * 4 + 0] += v.x; tot[q * 4 + 1] += v.y;
                tot[q * 4 + 2] += v.z; tot[q * 4 + 3] += v.w;
            }
        }
    } else {
        for (int k = 0; k < 16; k++) {
            int idx = tbase + k;
            if (idx < n)
                for (int c = 0; c < 8; c++) tot[k] += cnt8[(size_t)c * n + idx];
        }
    }
    int s = 0;
#pragma unroll
    for (int k = 0; k < 16; k++) s += tot[k];
    ls[threadIdx.x] = s;
    __syncthreads();
    for (int off = 1; off < 256; off <<= 1) {
        int t = threadIdx.x >= off ? ls[threadIdx.x - off] : 0;
        __syncthreads();
        ls[threadIdx.x] += t;
        __syncthreads();
    }
    int run = ls[threadIdx.x] - s;
    if (threadIdx.x == 255) bsums[blockIdx.x] = ls[255];
#pragma unroll
    for (int k = 0; k < 16; k++) {
        int idx = tbase + k;
        if (idx < n) starts[idx] = run;
        run += tot[k];
    }
}

// scan3: add cross-block prefix, set starts[n], convert cnt8 in place to
// per-copy scatter bases.
__global__ __launch_bounds__(256) void scan3(int* __restrict__ starts,
                                             const int* __restrict__ bsums,
                                             int* __restrict__ cnt8,
                                             int n, int ne) {
    __shared__ int base_s;
    int i = blockIdx.x * 256 + threadIdx.x;
    if (threadIdx.x == 0) {
        int reg = (int)(blockIdx.x >> 4);          // 4096-region = 16 blocks
        int s = 0;
        for (int b = 0; b < reg; b++) s += bsums[b];
        base_s = s;
        if (blockIdx.x == 0) starts[n] = ne;
    }
    __syncthreads();
    if (i >= n) return;
    int b = starts[i] + base_s;
    starts[i] = b;
#pragma unroll
    for (int c = 0; c < 8; c++) {
        size_t off = (size_t)c * n + i;
        int t = cnt8[off];
        cnt8[off] = b;
        b += t;
    }
}

// ------- scatter src into CSR (rank + per-copy base, 8 edges/thread) -----
__global__ __launch_bounds__(256) void scatter8_kernel(const int* __restrict__ src,
                                                       const int* __restrict__ dst,
                                                       const int* __restrict__ cnt8,
                                                       const unsigned short* __restrict__ rank,
                                                       int* __restrict__ csr_src,
                                                       int n, int ne) {
    int i = blockIdx.x * 256 + threadIdx.x;
    int base = i * 8;
    if (base + 7 < ne) {
        const int* __restrict__ cb = cnt8 + (size_t)((base >> 10) & 7) * n;
        int4 s0 = *(const int4*)(src + base),  s1 = *(const int4*)(src + base + 4);
        int4 d0 = *(const int4*)(dst + base),  d1 = *(const int4*)(dst + base + 4);
        uint4 rp = *(const uint4*)(rank + base);   // 8 ushorts
        csr_src[cb[d0.x] + (rp.x & 0xFFFF)] = s0.x;
        csr_src[cb[d0.y] + (rp.x >> 16)]    = s0.y;
        csr_src[cb[d0.z] + (rp.y & 0xFFFF)] = s0.z;
        csr_src[cb[d0.w] + (rp.y >> 16)]    = s0.w;
        csr_src[cb[d1.x] + (rp.z & 0xFFFF)] = s1.x;
        csr_src[cb[d1.y] + (rp.z >> 16)]    = s1.y;
        csr_src[cb[d1.z] + (rp.w & 0xFFFF)] = s1.z;
        csr_src[cb[d1.w] + (rp.w >> 16)]    = s1.w;
    } else {
        for (int e = base; e < ne; e++) {
            const int* cb = cnt8 + (size_t)((e >> 10) & 7) * n;
            csr_src[cb[dst[e]] + rank[e]] = src[e];
        }
    }
}

// ---------- fused: MFMA dot + online softmax + aggregation + elu ---------
// One wave per node. Per 16-edge chunk: A-frag = 16 gathered z_src rows
// (lane: row=lane&15, k-octet=lane>>4 — the verified r22 gemm mapping),
// B-frag = z_dst broadcast over cols (D cols replicate => every lane holds
// its group's 4 edge-dots in acc[0..3], no cross-lane reduce). Wave-max via
// 2 shfl; exp2 online softmax; agg keeps 1-fma/edge with q4-quad regather.
__global__ __launch_bounds__(256) void fused_node(const unsigned short* __restrict__ zh,
                                                  const int* __restrict__ starts,
                                                  const int* __restrict__ csr_src,
                                                  float4* __restrict__ out4, int n) {
    int node = blockIdx.x * 4 + (threadIdx.x >> 6);
    if (node >= n) return;
    int lane = threadIdx.x & 63;
    int g4 = lane >> 4;       // k-octet for MFMA; edge-quad owner for agg
    int q4 = lane & 15;       // A edge-row for MFMA gather; ch-quad for agg
    int rs = starts[node], re = starts[node + 1];

    const unsigned short* __restrict__ zdp = zh + (size_t)node * 64 + g4 * 8;
    half8_t bv0 = *(const half8_t*)(zdp);        // zd[k= 0..31], this octet
    half8_t bv1 = *(const half8_t*)(zdp + 32);   // zd[k=32..63], this octet

    float m = -1e30f, denom = 0.f;
    float4 out = make_float4(0.f, 0.f, 0.f, 0.f);

    for (int c = rs; c < re; c += 64) {
        int j = c + lane;
        int sv = j < re ? csr_src[j] : 0;
        int cn = min(64, re - c);
        for (int t = 0; t * 16 < cn; t++) {
            // ---- dot via MFMA: 16 edges, K=64 in 2 chunks ----
            int eidx = t * 16 + q4;
            int se = __shfl(sv, eidx < cn ? eidx : 0);
            const unsigned short* ap = zh + (size_t)se * 64 + g4 * 8;
            half8_t a0 = *(const half8_t*)(ap);
            half8_t a1 = *(const half8_t*)(ap + 32);
            f32x4_t acc = {0.f, 0.f, 0.f, 0.f};
            acc = __builtin_amdgcn_mfma_f32_16x16x32_f16(a0, bv0, acc, 0, 0, 0);
            acc = __builtin_amdgcn_mfma_f32_16x16x32_f16(a1, bv1, acc, 0, 0, 0);
            // lane's 4 edges: e = t*16 + g4*4 + jj   [m89 D row mapping]
            float e2[4];
            float cmax = -2e30f;
#pragma unroll
            for (int jj = 0; jj < 4; jj++) {
                float p = acc[jj];
                float e = fmaxf(p, SLOPE * p) * LOG2E;   // leaky, exp2 domain
                bool v = (t * 16 + g4 * 4 + jj) < cn;
                e2[jj] = v ? e : -2e30f;
                cmax = fmaxf(cmax, e2[jj]);
            }
            cmax = fmaxf(cmax, __shfl_xor(cmax, 16));
            cmax = fmaxf(cmax, __shfl_xor(cmax, 32));   // wave-uniform chunk max
            if (cmax > m) {                              // uniform branch
                float sc = exp2f(m - cmax);              // 0 on first chunk
                denom *= sc;
                out.x *= sc; out.y *= sc; out.z *= sc; out.w *= sc;
                m = cmax;
            }
            float ex[4];
#pragma unroll
            for (int jj = 0; jj < 4; jj++) {
                ex[jj] = exp2f(e2[jj] - m);              // 0 for invalid slots
                denom += ex[jj];
            }
            // ---- aggregation: lane owns ch-quad q4 of its group's edges ----
#pragma unroll
            for (int jj = 0; jj < 4; jj++) {
                int ei = t * 16 + g4 * 4 + jj;
                int sa = __shfl(sv, ei < cn ? ei : 0);   // ex=0 kills invalid
                uint2 w = *(const uint2*)(zh + (size_t)sa * 64 + q4 * 4);
                half2_t lo = u2h2(w.x), hi = u2h2(w.y);
                out.x = fmaf(ex[jj], (float)lo[0], out.x);
                out.y = fmaf(ex[jj], (float)lo[1], out.y);
                out.z = fmaf(ex[jj], (float)hi[0], out.z);
                out.w = fmaf(ex[jj], (float)hi[1], out.w);
            }
        }
    }
    // merge the 4 k-groups (lane = g4*16+q4: masks 16,32 flip g4 only)
#pragma unroll
    for (int msk = 16; msk < 64; msk <<= 1) {
        denom += __shfl_xor(denom, msk);
        out.x += __shfl_xor(out.x, msk);
        out.y += __shfl_xor(out.y, msk);
        out.z += __shfl_xor(out.z, msk);
        out.w += __shfl_xor(out.w, msk);
    }
    if (g4 == 0) {
        float inv = denom > 0.f ? 1.f / denom : 0.f;
        float4 r;
        float x;
        x = out.x * inv; r.x = x > 0.f ? x : __expf(x) - 1.f;
        x = out.y * inv; r.y = x > 0.f ? x : __expf(x) - 1.f;
        x = out.z * inv; r.z = x > 0.f ? x : __expf(x) - 1.f;
        x = out.w * inv; r.w = x > 0.f ? x : __expf(x) - 1.f;
        out4[(size_t)node * 16 + q4] = r;                // coalesced 256B/node
    }
}

// -------------------------------------------------------------- launch ----
extern "C" void kernel_launch(void* const* d_in, const int* in_sizes, int n_in,
                              void* d_out, int out_size, void* d_ws, size_t ws_size,
                              hipStream_t stream) {
    const float* h   = (const float*)d_in[0];
    const float* W   = (const float*)d_in[1];
    const int*   src = (const int*)d_in[2];
    const int*   dst = (const int*)d_in[3];
    int n  = in_sizes[0] / 128;   // 100000
    int ne = in_sizes[2];         // 1600000

    // 16B-aligned layout (~26 MB): zh | rank | cnt8 | csr_src | Wh | starts
    unsigned short* zh      = (unsigned short*)d_ws;             // 12.8 MB
    unsigned short* rank    = zh + (size_t)n * 64;               // 3.2 MB
    int*            cnt8    = (int*)(rank + ne);                 // 3.2 MB
    int*            csr_src = cnt8 + (size_t)8 * n;              // 6.4 MB
    unsigned short* Wh      = (unsigned short*)(csr_src + ne);   // 16 KB
    int*            starts  = (int*)(Wh + 64 * 128);             // n+1
    int*            bsums   = starts + ((n + 5) & ~3);           // 32

    int nGemm = (n + 15) / 16;                        // 6250
    int nbHist = (ne / 4 + 255) / 256;                // 1563
    int nbTotal = nbHist * 5;                         // 7815
    int nb_scan = (n + 4095) / 4096;                  // 25

    hipMemsetAsync(cnt8, 0, (size_t)8 * n * sizeof(int), stream);
    wcvt_kernel<<<(64 * 128 / 4 + 255) / 256, 256, 0, stream>>>(W, Wh, 64 * 128 / 4);
    gemm_hist_kernel<<<nbTotal, 256, 0, stream>>>(h, Wh, zh, dst, cnt8, rank,
                                                  n, ne, nGemm);
    scan1<<<nb_scan, 256, 0, stream>>>(cnt8, starts, bsums, n);
    scan3<<<(n + 255) / 256, 256, 0, stream>>>(starts, bsums, cnt8, n, ne);
    scatter8_kernel<<<(ne / 8 + 255) / 256, 256, 0, stream>>>(src, dst, cnt8,
                                                              rank, csr_src, n, ne);
    fused_node<<<(n + 3) / 4, 256, 0, stream>>>(zh, starts, csr_src,
                                                (float4*)d_out, n);
}

// Round 29
// 183.095 us; speedup vs baseline: 1.1307x; 1.0104x over previous
//
#include <hip/hip_runtime.h>
#include <hip/hip_fp16.h>
#include <math.h>

#define SLOPE 0.2f
#define LOG2E 1.4426950408889634f

typedef _Float16 half8_t __attribute__((ext_vector_type(8)));
typedef _Float16 half2_t __attribute__((ext_vector_type(2)));
typedef float    f32x4_t __attribute__((ext_vector_type(4)));

__device__ __forceinline__ unsigned short pk_f16(float x) {
    return __half_as_ushort(__float2half(x));
}
__device__ __forceinline__ half2_t u2h2(unsigned int u) {
    union { unsigned int u; half2_t h; } c; c.u = u; return c.h;
}

// ---------- interleaved MFMA-gemm ∥ XCD-private histogram ----------------
// blockIdx%3==2 -> histogram block g=blockIdx/3: 2 edges/thread (512/block,
// 3126 blocks = 2x the concurrency of r28) into cnt8[g&7]; rank(ushort) =
// atomic return. Else gemm block gemmIdx = (blockIdx/3)*2 + blockIdx%3:
// 16 nodes x 64 ch; wave w = 16x16 D-tile at ch0=16w via 4x
// mfma_f32_16x16x32_f16 (K=128); W loaded f32 + converted in-reg (L3-hot).
// C/D: node = n0 + (lane>>4)*4 + r, ch = ch0 + (lane&15)   [m89 layout]
__global__ __launch_bounds__(256, 8) void gemm_hist_kernel(const float* __restrict__ h,
                                                           const float* __restrict__ W,
                                                           unsigned short* __restrict__ zh,
                                                           const int* __restrict__ dst,
                                                           int* __restrict__ cnt8,
                                                           unsigned short* __restrict__ rank,
                                                           int n, int ne) {
    int r3 = blockIdx.x % 3;
    int g3 = blockIdx.x / 3;
    if (r3 == 2) {
        // ---- histogram block ----
        int* __restrict__ cnt = cnt8 + (size_t)(g3 & 7) * n;
        int i = g3 * 256 + threadIdx.x;
        int base = i * 2;
        if (base + 1 < ne) {
            int2 d = *(const int2*)(dst + base);
            unsigned int r0 = atomicAdd(&cnt[d.x], 1);
            unsigned int r1 = atomicAdd(&cnt[d.y], 1);
            *(unsigned int*)(rank + base) = (r1 << 16) | (r0 & 0xFFFF);
        } else if (base < ne) {
            rank[base] = (unsigned short)atomicAdd(&cnt[dst[base]], 1);
        }
        return;
    }

    // ---- gemm block (MFMA) ----
    int gemmIdx = g3 * 2 + r3;
    int n0 = gemmIdx * 16;
    if (n0 >= n) return;
    int lane = threadIdx.x & 63;
    int wave = threadIdx.x >> 6;
    int row = lane & 15;          // A row (node) and B col (channel)
    int grp = lane >> 4;          // k-group
    int ch0 = wave * 16;

    const float* __restrict__ hp = h + (size_t)(n0 + row) * 128 + grp * 8;
    const float* __restrict__ wp = W + (size_t)(ch0 + row) * 128 + grp * 8;

    f32x4_t acc = {0.f, 0.f, 0.f, 0.f};
#pragma unroll
    for (int c = 0; c < 4; c++) {
        int kc = c * 32;
        float4 a0 = *(const float4*)(hp + kc);
        float4 a1 = *(const float4*)(hp + kc + 4);
        half8_t av;
        av[0] = (_Float16)a0.x; av[1] = (_Float16)a0.y;
        av[2] = (_Float16)a0.z; av[3] = (_Float16)a0.w;
        av[4] = (_Float16)a1.x; av[5] = (_Float16)a1.y;
        av[6] = (_Float16)a1.z; av[7] = (_Float16)a1.w;
        float4 b0 = *(const float4*)(wp + kc);
        float4 b1 = *(const float4*)(wp + kc + 4);
        half8_t bv;
        bv[0] = (_Float16)b0.x; bv[1] = (_Float16)b0.y;
        bv[2] = (_Float16)b0.z; bv[3] = (_Float16)b0.w;
        bv[4] = (_Float16)b1.x; bv[5] = (_Float16)b1.y;
        bv[6] = (_Float16)b1.z; bv[7] = (_Float16)b1.w;
        acc = __builtin_amdgcn_mfma_f32_16x16x32_f16(av, bv, acc, 0, 0, 0);
    }
#pragma unroll
    for (int r = 0; r < 4; r++)
        zh[(size_t)(n0 + grp * 4 + r) * 64 + ch0 + row] = pk_f16(acc[r]);
}

// -------------------- scan over 8-copy histogram (4096/block) ------------
__global__ __launch_bounds__(256) void scan1(const int* __restrict__ cnt8,
                                             int* __restrict__ starts,
                                             int* __restrict__ bsums, int n) {
    __shared__ int ls[256];
    int tbase = blockIdx.x * 4096 + threadIdx.x * 16;
    int tot[16];
#pragma unroll
    for (int k = 0; k < 16; k++) tot[k] = 0;
    if (tbase + 15 < n) {
#pragma unroll
        for (int c = 0; c < 8; c++) {
            const int* cp = cnt8 + (size_t)c * n + tbase;
#pragma unroll
            for (int q = 0; q < 4; q++) {
                int4 v = *(const int4*)(cp + q * 4);
                tot[q * 4 + 0] += v.x; tot[q * 4 + 1] += v.y;
                tot[q * 4 + 2] += v.z; tot[q * 4 + 3] += v.w;
            }
        }
    } else {
        for (int k = 0; k < 16; k++) {
            int idx = tbase + k;
            if (idx < n)
                for (int c = 0; c < 8; c++) tot[k] += cnt8[(size_t)c * n + idx];
        }
    }
    int s = 0;
#pragma unroll
    for (int k = 0; k < 16; k++) s += tot[k];
    ls[threadIdx.x] = s;
    __syncthreads();
    for (int off = 1; off < 256; off <<= 1) {
        int t = threadIdx.x >= off ? ls[threadIdx.x - off] : 0;
        __syncthreads();
        ls[threadIdx.x] += t;
        __syncthreads();
    }
    int run = ls[threadIdx.x] - s;
    if (threadIdx.x == 255) bsums[blockIdx.x] = ls[255];
#pragma unroll
    for (int k = 0; k < 16; k++) {
        int idx = tbase + k;
        if (idx < n) starts[idx] = run;
        run += tot[k];
    }
}

// scan3: add cross-block prefix, set starts[n], convert cnt8 in place to
// per-copy scatter bases.
__global__ __launch_bounds__(256) void scan3(int* __restrict__ starts,
                                             const int* __restrict__ bsums,
                                             int* __restrict__ cnt8,
                                             int n, int ne) {
    __shared__ int base_s;
    int i = blockIdx.x * 256 + threadIdx.x;
    if (threadIdx.x == 0) {
        int reg = (int)(blockIdx.x >> 4);          // 4096-region = 16 blocks
        int s = 0;
        for (int b = 0; b < reg; b++) s += bsums[b];
        base_s = s;
        if (blockIdx.x == 0) starts[n] = ne;
    }
    __syncthreads();
    if (i >= n) return;
    int b = starts[i] + base_s;
    starts[i] = b;
#pragma unroll
    for (int c = 0; c < 8; c++) {
        size_t off = (size_t)c * n + i;
        int t = cnt8[off];
        cnt8[off] = b;
        b += t;
    }
}

// ------- scatter src into CSR (rank + per-copy base, 8 edges/thread) -----
// copy of edge e = (e>>9)&7 (hist blocks own 512-edge chunks). 8-aligned
// groups never straddle a chunk boundary.
__global__ __launch_bounds__(256) void scatter8_kernel(const int* __restrict__ src,
                                                       const int* __restrict__ dst,
                                                       const int* __restrict__ cnt8,
                                                       const unsigned short* __restrict__ rank,
                                                       int* __restrict__ csr_src,
                                                       int n, int ne) {
    int i = blockIdx.x * 256 + threadIdx.x;
    int base = i * 8;
    if (base + 7 < ne) {
        const int* __restrict__ cb = cnt8 + (size_t)((base >> 9) & 7) * n;
        int4 s0 = *(const int4*)(src + base),  s1 = *(const int4*)(src + base + 4);
        int4 d0 = *(const int4*)(dst + base),  d1 = *(const int4*)(dst + base + 4);
        uint4 rp = *(const uint4*)(rank + base);   // 8 ushorts
        csr_src[cb[d0.x] + (rp.x & 0xFFFF)] = s0.x;
        csr_src[cb[d0.y] + (rp.x >> 16)]    = s0.y;
        csr_src[cb[d0.z] + (rp.y & 0xFFFF)] = s0.z;
        csr_src[cb[d0.w] + (rp.y >> 16)]    = s0.w;
        csr_src[cb[d1.x] + (rp.z & 0xFFFF)] = s1.x;
        csr_src[cb[d1.y] + (rp.z >> 16)]    = s1.y;
        csr_src[cb[d1.z] + (rp.w & 0xFFFF)] = s1.z;
        csr_src[cb[d1.w] + (rp.w >> 16)]    = s1.w;
    } else {
        for (int e = base; e < ne; e++) {
            const int* cb = cnt8 + (size_t)((e >> 9) & 7) * n;
            csr_src[cb[dst[e]] + rank[e]] = src[e];
        }
    }
}

// ---------- fused: MFMA dot + online softmax + aggregation + elu ---------
// One wave per node. Per 16-edge chunk: A-frag = 16 gathered z_src rows
// (lane: row=lane&15, k-octet=lane>>4), B-frag = z_dst broadcast over cols
// (D cols replicate => lane holds its group's 4 edge-dots in acc[0..3]).
__global__ __launch_bounds__(256) void fused_node(const unsigned short* __restrict__ zh,
                                                  const int* __restrict__ starts,
                                                  const int* __restrict__ csr_src,
                                                  float4* __restrict__ out4, int n) {
    int node = blockIdx.x * 4 + (threadIdx.x >> 6);
    if (node >= n) return;
    int lane = threadIdx.x & 63;
    int g4 = lane >> 4;       // k-octet for MFMA; edge-quad owner for agg
    int q4 = lane & 15;       // A edge-row for MFMA gather; ch-quad for agg
    int rs = starts[node], re = starts[node + 1];

    const unsigned short* __restrict__ zdp = zh + (size_t)node * 64 + g4 * 8;
    half8_t bv0 = *(const half8_t*)(zdp);        // zd[k= 0..31], this octet
    half8_t bv1 = *(const half8_t*)(zdp + 32);   // zd[k=32..63], this octet

    float m = -1e30f, denom = 0.f;
    float4 out = make_float4(0.f, 0.f, 0.f, 0.f);

    for (int c = rs; c < re; c += 64) {
        int j = c + lane;
        int sv = j < re ? csr_src[j] : 0;
        int cn = min(64, re - c);
        for (int t = 0; t * 16 < cn; t++) {
            // ---- dot via MFMA: 16 edges, K=64 in 2 chunks ----
            int eidx = t * 16 + q4;
            int se = __shfl(sv, eidx < cn ? eidx : 0);
            const unsigned short* ap = zh + (size_t)se * 64 + g4 * 8;
            half8_t a0 = *(const half8_t*)(ap);
            half8_t a1 = *(const half8_t*)(ap + 32);
            f32x4_t acc = {0.f, 0.f, 0.f, 0.f};
            acc = __builtin_amdgcn_mfma_f32_16x16x32_f16(a0, bv0, acc, 0, 0, 0);
            acc = __builtin_amdgcn_mfma_f32_16x16x32_f16(a1, bv1, acc, 0, 0, 0);
            // lane's 4 edges: e = t*16 + g4*4 + jj   [m89 D row mapping]
            float e2[4];
            float cmax = -2e30f;
#pragma unroll
            for (int jj = 0; jj < 4; jj++) {
                float p = acc[jj];
                float e = fmaxf(p, SLOPE * p) * LOG2E;   // leaky, exp2 domain
                bool v = (t * 16 + g4 * 4 + jj) < cn;
                e2[jj] = v ? e : -2e30f;
                cmax = fmaxf(cmax, e2[jj]);
            }
            cmax = fmaxf(cmax, __shfl_xor(cmax, 16));
            cmax = fmaxf(cmax, __shfl_xor(cmax, 32));   // wave-uniform chunk max
            if (cmax > m) {                              // uniform branch
                float sc = exp2f(m - cmax);              // 0 on first chunk
                denom *= sc;
                out.x *= sc; out.y *= sc; out.z *= sc; out.w *= sc;
                m = cmax;
            }
            float ex[4];
#pragma unroll
            for (int jj = 0; jj < 4; jj++) {
                ex[jj] = exp2f(e2[jj] - m);              // 0 for invalid slots
                denom += ex[jj];
            }
            // ---- aggregation: lane owns ch-quad q4 of its group's edges ----
#pragma unroll
            for (int jj = 0; jj < 4; jj++) {
                int ei = t * 16 + g4 * 4 + jj;
                int sa = __shfl(sv, ei < cn ? ei : 0);   // ex=0 kills invalid
                uint2 w = *(const uint2*)(zh + (size_t)sa * 64 + q4 * 4);
                half2_t lo = u2h2(w.x), hi = u2h2(w.y);
                out.x = fmaf(ex[jj], (float)lo[0], out.x);
                out.y = fmaf(ex[jj], (float)lo[1], out.y);
                out.z = fmaf(ex[jj], (float)hi[0], out.z);
                out.w = fmaf(ex[jj], (float)hi[1], out.w);
            }
        }
    }
    // merge the 4 k-groups (lane = g4*16+q4: masks 16,32 flip g4 only)
#pragma unroll
    for (int msk = 16; msk < 64; msk <<= 1) {
        denom += __shfl_xor(denom, msk);
        out.x += __shfl_xor(out.x, msk);
        out.y += __shfl_xor(out.y, msk);
        out.z += __shfl_xor(out.z, msk);
        out.w += __shfl_xor(out.w, msk);
    }
    if (g4 == 0) {
        float inv = denom > 0.f ? 1.f / denom : 0.f;
        float4 r;
        float x;
        x = out.x * inv; r.x = x > 0.f ? x : __expf(x) - 1.f;
        x = out.y * inv; r.y = x > 0.f ? x : __expf(x) - 1.f;
        x = out.z * inv; r.z = x > 0.f ? x : __expf(x) - 1.f;
        x = out.w * inv; r.w = x > 0.f ? x : __expf(x) - 1.f;
        out4[(size_t)node * 16 + q4] = r;                // coalesced 256B/node
    }
}

// -------------------------------------------------------------- launch ----
extern "C" void kernel_launch(void* const* d_in, const int* in_sizes, int n_in,
                              void* d_out, int out_size, void* d_ws, size_t ws_size,
                              hipStream_t stream) {
    const float* h   = (const float*)d_in[0];
    const float* W   = (const float*)d_in[1];
    const int*   src = (const int*)d_in[2];
    const int*   dst = (const int*)d_in[3];
    int n  = in_sizes[0] / 128;   // 100000
    int ne = in_sizes[2];         // 1600000

    // 16B-aligned layout (~26 MB): zh | rank | cnt8 | csr_src | starts
    unsigned short* zh      = (unsigned short*)d_ws;             // 12.8 MB
    unsigned short* rank    = zh + (size_t)n * 64;               // 3.2 MB
    int*            cnt8    = (int*)(rank + ne);                 // 3.2 MB
    int*            csr_src = cnt8 + (size_t)8 * n;              // 6.4 MB
    int*            starts  = csr_src + ne;                      // n+1
    int*            bsums   = starts + ((n + 5) & ~3);           // 32

    int nbHist = (ne / 2 + 255) / 256;                // 3125
    int nbTotal = (nbHist + 1) * 3;                   // 9378 (gemm = 6252)
    int nb_scan = (n + 4095) / 4096;                  // 25

    hipMemsetAsync(cnt8, 0, (size_t)8 * n * sizeof(int), stream);
    gemm_hist_kernel<<<nbTotal, 256, 0, stream>>>(h, W, zh, dst, cnt8, rank, n, ne);
    scan1<<<nb_scan, 256, 0, stream>>>(cnt8, starts, bsums, n);
    scan3<<<(n + 255) / 256, 256, 0, stream>>>(starts, bsums, cnt8, n, ne);
    scatter8_kernel<<<(ne / 8 + 255) / 256, 256, 0, stream>>>(src, dst, cnt8,
                                                              rank, csr_src, n, ne);
    fused_node<<<(n + 3) / 4, 256, 0, stream>>>(zh, starts, csr_src,
                                                (float4*)d_out, n);
}